// Round 14
// baseline (496.020 us; speedup 1.0000x reference)
//
#include <hip/hip_runtime.h>
#include <math.h>

#define J_ 24
#define T_ 256
#define B_ 32

typedef short short8v __attribute__((ext_vector_type(8)));   // 8 x bf16 (4 VGPR)
typedef float f32x4  __attribute__((ext_vector_type(4)));    // MFMA acc

__device__ __forceinline__ short f2bf(float f) {
    unsigned u = __float_as_uint(f);
    u += 0x7fffu + ((u >> 16) & 1u);          // round-to-nearest-even
    return (short)(u >> 16);
}
__device__ __forceinline__ float bf2f(short s) {
    return __uint_as_float(((unsigned)(unsigned short)s) << 16);
}

// direct global->LDS DMA: dest = wave-uniform base + lane*16 (linear), source per-lane
__device__ __forceinline__ void gload_lds16(const void* gsrc, void* ldst) {
    __builtin_amdgcn_global_load_lds(
        (const __attribute__((address_space(1))) void*)gsrc,
        (__attribute__((address_space(3))) void*)ldst, 16, 0, 0);
}

__device__ __constant__ int d_parent[24] = {-1,0,0,0,1,2,3,4,5,6,7,8,9,9,9,12,13,14,16,17,18,19,20,21};

// ---------------------------------------------------------------- adjacency tables
__global__ void adj_init_kernel(float* __restrict__ adj_out, short* __restrict__ amix) {
    __shared__ float s_adj[576];
    const int tid = threadIdx.x;
    for (int i = tid; i < 576; i += 256) {
        const int j = i / 24, k = i % 24;
        float a = (j == k || d_parent[k] == j || d_parent[j] == k) ? 1.f : 0.f;
        float d = 0.f;
        for (int kk = 0; kk < 24; ++kk)
            d += (j == kk || d_parent[kk] == j || d_parent[j] == kk) ? 1.f : 0.f;
        const float v = a / fmaxf(d, 1.f);
        s_adj[i] = v;
        adj_out[i] = v;
    }
    __syncthreads();
    if (tid < 24) {
        float cs = 0.f;
        for (int j = 0; j < 24; ++j) cs += s_adj[j*24 + tid];
        adj_out[576 + tid] = cs;
        int n = 0;
        for (int j = 0; j < 24; ++j) {
            const float w = s_adj[j*24 + tid];
            if (w != 0.f && n < 8) {
                adj_out[600 + tid*8 + n] = w;
                adj_out[792 + tid*8 + n] = (float)j;
                ++n;
            }
        }
        for (; n < 8; ++n) { adj_out[600 + tid*8 + n] = 0.f; adj_out[792 + tid*8 + n] = 0.f; }
    }
    __syncthreads();
    for (int i = tid; i < 96*96; i += 256) {
        const int r = i / 96, j = i % 96;
        float v = 0.f;
        if (r / 24 == j / 24) v = s_adj[(j % 24) * 24 + (r % 24)];
        amix[i] = f2bf(v);
    }
}

// ---------------------------------------------------------------- fused weight prep
__global__ __launch_bounds__(256) void prep_kernel(
    const float* __restrict__ w1t, const float* __restrict__ bn1_2,
    const float* __restrict__ w2t, const float* __restrict__ bn2_2,
    const float* __restrict__ w3t, const float* __restrict__ bn3_2,
    const float* __restrict__ g2w, const float* __restrict__ bn2_1,
    const float* __restrict__ g3w, const float* __restrict__ bn3_1,
    const float* __restrict__ r3w,
    const float* __restrict__ g1w, const float* __restrict__ bn1_1,
    const float* __restrict__ r1w,
    short* __restrict__ wt1b, short* __restrict__ wt2b, short* __restrict__ wt3b,
    short* __restrict__ gw2b, short* __restrict__ gw3b, short* __restrict__ rw3b,
    short* __restrict__ gw1b, short* __restrict__ rw1b)
{
    const int i = blockIdx.x * 256 + threadIdx.x;
    if (i < 49152) {
        const int o = i / 384, r = i % 384, dt = r / 128, c = r % 128;
        const float s = bn1_2[o] * rsqrtf(bn1_2[384 + o] + 1e-5f);
        wt1b[i] = f2bf(s * w1t[(o*128 + c)*3 + dt]);
    } else if (i < 98304) {
        const int j = i - 49152;
        const int o = j / 384, r = j % 384, dt = r / 128, c = r % 128;
        const float s = bn2_2[o] * rsqrtf(bn2_2[384 + o] + 1e-5f);
        wt2b[j] = f2bf(s * w2t[(o*128 + c)*3 + dt]);
    } else if (i < 294912) {
        const int j = i - 98304;
        const int o = j / 768, r = j % 768, dt = r / 256, c = r % 256;
        const float s = bn3_2[o] * rsqrtf(bn3_2[768 + o] + 1e-5f);
        wt3b[j] = f2bf(s * w3t[(o*256 + c)*3 + dt]);
    } else if (i < 311296) {
        const int j = i - 294912;
        const int o = j / 128;
        const float s = bn2_1[o] * rsqrtf(bn2_1[384 + o] + 1e-5f);
        gw2b[j] = f2bf(s * g2w[j]);
    } else if (i < 344064) {
        const int j = i - 311296;
        const int o = j / 128;
        const float s = bn3_1[o] * rsqrtf(bn3_1[768 + o] + 1e-5f);
        gw3b[j] = f2bf(s * g3w[j]);
    } else if (i < 376832) {
        const int j = i - 344064;
        rw3b[j] = f2bf(r3w[j]);
    } else if (i < 378880) {
        const int j = i - 376832;
        const int o = j / 8, c = j & 7;
        const float s = bn1_1[o] * rsqrtf(bn1_1[384 + o] + 1e-5f);
        gw1b[j] = (c < 6) ? f2bf(s * g1w[o*6 + c]) : (short)0;
    } else if (i < 380928) {
        const int j = i - 378880;
        const int o = j / 8, c = j & 7;
        rw1b[j] = (c < 6) ? f2bf(r1w[o*6 + c]) : (short)0;
    }
}

// LDS layout (block1/block2), 52,832 B
#define LDS_SZ   52832
#define FA_OFF   26624
#define FT_STRIDE 208
#define X6B_OFF  40320
#define XA6B_OFF 44928
#define TBL_OFF  51200

// ================================================================ KERNEL 1 (512 thr)  [unchanged]
__global__ __launch_bounds__(512) void block1_kernel(
    const float* __restrict__ x,
    const short* __restrict__ gw1b, const float* __restrict__ gb1, const float* __restrict__ bn1,
    const short* __restrict__ rw1b, const float* __restrict__ rb1,
    const float* __restrict__ bn12, const float* __restrict__ tb1, const short* __restrict__ wt1b,
    const short* __restrict__ gw2b, const float* __restrict__ gb2, const float* __restrict__ bn21,
    const float* __restrict__ adjp, const short* __restrict__ amix,
    short* __restrict__ f1_out, short* __restrict__ h2_out)
{
    __shared__ char smem[LDS_SZ];
    short* s_x6b  = (short*)(smem + X6B_OFF);
    short* s_xa6b = (short*)(smem + XA6B_OFF);
    float* s_cw  = (float*)(smem + TBL_OFF);
    int*   s_ci  = (int*)  (smem + TBL_OFF + 768);
    float* s_cs  = (float*)(smem + TBL_OFF + 1536);

    const int r0 = blockIdx.x * 96;
    const int bstart = (r0 / 6144) * 6144;
    const int bend = bstart + 6144;
    const int tid = threadIdx.x;
    const int l = tid & 63, wid = tid >> 6;
    const int m0w = (wid >> 2) * 48;
    const int n0w = (wid & 3) * 32;
    const int lr = l & 15, lk = l >> 4;
    const short8v z8 = {0,0,0,0,0,0,0,0};

    if (tid < 192) { s_cw[tid] = adjp[600 + tid]; s_ci[tid] = (int)adjp[792 + tid]; }
    else if (tid < 216) s_cs[tid - 192] = adjp[576 + (tid - 192)];
    if (tid < 144) {
        const int gr = r0 - 24 + tid;
        short8v v = z8;
        if (gr >= bstart && gr < bend) {
            const float ax = x[gr*3+0], ay = x[gr*3+1], az = x[gr*3+2];
            const float angle = sqrtf(ax*ax + ay*ay + az*az);
            const float inv = 1.f / (angle + 1e-8f);
            const float ux = ax*inv, uy = ay*inv, uz = az*inv;
            const float c = cosf(angle), s = sinf(angle), omc = 1.f - c;
            v[0] = f2bf(c + omc*ux*ux);   v[1] = f2bf(omc*ux*uy - s*uz);
            v[2] = f2bf(omc*uy*ux + s*uz); v[3] = f2bf(c + omc*uy*uy);
            v[4] = f2bf(omc*uz*ux - s*uy); v[5] = f2bf(omc*uz*uy + s*ux);
        }
        *(short8v*)(s_x6b + tid*8) = v;
    }
    __syncthreads();
    if (tid < 144) {
        const int k = tid % 24, sl = (tid / 24) * 24;
        float a[6] = {0,0,0,0,0,0};
        #pragma unroll
        for (int u = 0; u < 8; ++u) {
            const float wgt = s_cw[k*8+u];
            const short8v v = *(const short8v*)(s_x6b + (sl + s_ci[k*8+u])*8);
            #pragma unroll
            for (int e = 0; e < 6; ++e) a[e] = fmaf(wgt, bf2f(v[e]), a[e]);
        }
        short8v o8 = z8;
        #pragma unroll
        for (int e = 0; e < 6; ++e) o8[e] = f2bf(a[e]);
        *(short8v*)(s_xa6b + tid*8) = o8;
    }
    __syncthreads();
    {
        const int col = wid*16 + lr;
        short8v bfr = z8;
        if (lk == 0) bfr = *(const short8v*)(gw1b + (size_t)col*8);
        f32x4 cacc[9];
        #pragma unroll
        for (int mi = 0; mi < 9; ++mi) cacc[mi] = (f32x4){0.f,0.f,0.f,0.f};
        #pragma unroll
        for (int mi = 0; mi < 9; ++mi) {
            short8v afr = z8;
            if (lk == 0) afr = *(const short8v*)(s_xa6b + (mi*16 + lr)*8);
            cacc[mi] = __builtin_amdgcn_mfma_f32_16x16x32_bf16(afr, bfr, cacc[mi], 0, 0, 0);
        }
        const float s1 = bn1[col] * rsqrtf(bn1[384 + col] + 1e-5f);
        const float t1 = bn1[128 + col] - bn1[256 + col] * s1;
        const float g1 = s1 * gb1[col];
        const int ch2 = col * 2;
        #pragma unroll
        for (int mi = 0; mi < 9; ++mi)
            #pragma unroll
            for (int rg = 0; rg < 4; ++rg) {
                const int row = mi*16 + lk*4 + rg;
                const int gr = r0 - 24 + row;
                short hv = 0;
                if (gr >= bstart && gr < bend)
                    hv = f2bf(fmaxf(cacc[mi][rg] + t1 + g1*s_cs[row % 24], 0.f));
                *(short*)(smem + row*256 + ((ch2 & 0xF0) ^ ((row&7)<<4)) + (ch2 & 14)) = hv;
            }
    }
    __syncthreads();
    f32x4 acc[3][2];
    #pragma unroll
    for (int mi = 0; mi < 3; ++mi)
        #pragma unroll
        for (int ni = 0; ni < 2; ++ni) acc[mi][ni] = (f32x4){0.f,0.f,0.f,0.f};
    #pragma unroll
    for (int dt = 0; dt < 3; ++dt) {
        #pragma unroll
        for (int kc = 0; kc < 4; ++kc) {
            short8v bfr[2], afr[3];
            #pragma unroll
            for (int ni = 0; ni < 2; ++ni) {
                const int n = n0w + ni*16 + lr;
                bfr[ni] = *(const short8v*)(wt1b + (size_t)n*384 + dt*128 + kc*32 + lk*8);
            }
            #pragma unroll
            for (int mi = 0; mi < 3; ++mi) {
                const int row = m0w + dt*24 + mi*16 + lr;
                afr[mi] = *(const short8v*)(smem + row*256 + ((kc*64 + lk*16) ^ ((row&7)<<4)));
            }
            #pragma unroll
            for (int mi = 0; mi < 3; ++mi)
                #pragma unroll
                for (int ni = 0; ni < 2; ++ni)
                    acc[mi][ni] = __builtin_amdgcn_mfma_f32_16x16x32_bf16(afr[mi], bfr[ni], acc[mi][ni], 0, 0, 0);
        }
    }
    {
        short8v bfr[2], afr[3];
        #pragma unroll
        for (int ni = 0; ni < 2; ++ni) {
            bfr[ni] = z8;
            if (lk == 0) bfr[ni] = *(const short8v*)(rw1b + (size_t)(n0w + ni*16 + lr)*8);
        }
        #pragma unroll
        for (int mi = 0; mi < 3; ++mi) {
            afr[mi] = z8;
            if (lk == 0) afr[mi] = *(const short8v*)(s_x6b + (m0w + mi*16 + lr + 24)*8);
        }
        #pragma unroll
        for (int mi = 0; mi < 3; ++mi)
            #pragma unroll
            for (int ni = 0; ni < 2; ++ni)
                acc[mi][ni] = __builtin_amdgcn_mfma_f32_16x16x32_bf16(afr[mi], bfr[ni], acc[mi][ni], 0, 0, 0);
    }
    __syncthreads();
    #pragma unroll
    for (int ni = 0; ni < 2; ++ni) {
        const int o = n0w + ni*16 + lr;
        const float s2 = bn12[o] * rsqrtf(bn12[384 + o] + 1e-5f);
        const float bias = (bn12[128 + o] - bn12[256 + o]*s2) + s2*tb1[o] + rb1[o];
        #pragma unroll
        for (int mi = 0; mi < 3; ++mi)
            #pragma unroll
            for (int rg = 0; rg < 4; ++rg) {
                const int rl = m0w + mi*16 + lk*4 + rg;
                const short hv = f2bf(fmaxf(acc[mi][ni][rg] + bias, 0.f));
                f1_out[(size_t)(r0 + rl)*128 + o] = hv;
                *(short*)(smem + o*FT_STRIDE + rl*2) = hv;
            }
    }
    __syncthreads();
    {
        f32x4 pacc[3][2];
        #pragma unroll
        for (int mi = 0; mi < 3; ++mi)
            #pragma unroll
            for (int ni = 0; ni < 2; ++ni) pacc[mi][ni] = (f32x4){0.f,0.f,0.f,0.f};
        #pragma unroll
        for (int kc = 0; kc < 3; ++kc) {
            short8v bfr[2], afr[3];
            #pragma unroll
            for (int ni = 0; ni < 2; ++ni) {
                const int ch = n0w + ni*16 + lr;
                bfr[ni] = *(const short8v*)(smem + ch*FT_STRIDE + kc*64 + lk*16);
            }
            #pragma unroll
            for (int mi = 0; mi < 3; ++mi) {
                const int row = m0w + mi*16 + lr;
                afr[mi] = *(const short8v*)(amix + row*96 + kc*32 + lk*8);
            }
            #pragma unroll
            for (int mi = 0; mi < 3; ++mi)
                #pragma unroll
                for (int ni = 0; ni < 2; ++ni)
                    pacc[mi][ni] = __builtin_amdgcn_mfma_f32_16x16x32_bf16(afr[mi], bfr[ni], pacc[mi][ni], 0, 0, 0);
        }
        __syncthreads();
        #pragma unroll
        for (int ni = 0; ni < 2; ++ni) {
            const int ch2 = (n0w + ni*16 + lr) * 2;
            #pragma unroll
            for (int mi = 0; mi < 3; ++mi)
                #pragma unroll
                for (int rg = 0; rg < 4; ++rg) {
                    const int row = m0w + mi*16 + lk*4 + rg;
                    *(short*)(smem + FA_OFF + row*256 + ((ch2 & 0xF0) ^ ((row&7)<<4)) + (ch2 & 14)) =
                        f2bf(pacc[mi][ni][rg]);
                }
        }
    }
    __syncthreads();
    #pragma unroll
    for (int mi = 0; mi < 3; ++mi)
        #pragma unroll
        for (int ni = 0; ni < 2; ++ni) acc[mi][ni] = (f32x4){0.f,0.f,0.f,0.f};
    #pragma unroll
    for (int kc = 0; kc < 4; ++kc) {
        short8v bfr[2], afr[3];
        #pragma unroll
        for (int ni = 0; ni < 2; ++ni) {
            const int n = n0w + ni*16 + lr;
            bfr[ni] = *(const short8v*)(gw2b + (size_t)n*128 + kc*32 + lk*8);
        }
        #pragma unroll
        for (int mi = 0; mi < 3; ++mi) {
            const int row = m0w + mi*16 + lr;
            afr[mi] = *(const short8v*)(smem + FA_OFF + row*256 + ((kc*64 + lk*16) ^ ((row&7)<<4)));
        }
        #pragma unroll
        for (int mi = 0; mi < 3; ++mi)
            #pragma unroll
            for (int ni = 0; ni < 2; ++ni)
                acc[mi][ni] = __builtin_amdgcn_mfma_f32_16x16x32_bf16(afr[mi], bfr[ni], acc[mi][ni], 0, 0, 0);
    }
    #pragma unroll
    for (int ni = 0; ni < 2; ++ni) {
        const int o = n0w + ni*16 + lr;
        const float s = bn21[o] * rsqrtf(bn21[384 + o] + 1e-5f);
        const float t = bn21[128 + o] - bn21[256 + o]*s;
        const float g = s * gb2[o];
        #pragma unroll
        for (int mi = 0; mi < 3; ++mi)
            #pragma unroll
            for (int rg = 0; rg < 4; ++rg) {
                const int rl = m0w + mi*16 + lk*4 + rg;
                h2_out[(size_t)(r0 + rl)*128 + o] = f2bf(fmaxf(acc[mi][ni][rg] + t + g*s_cs[rl % 24], 0.f));
            }
    }
}

// ================================================================ KERNEL 2 (512 thr)
// h2 staged via DMA; f1 residual read from global (round-12 semantics — no LDS overlap)
__global__ __launch_bounds__(512) void block2_kernel(
    const short* __restrict__ h2, const short* __restrict__ wt2b,
    const float* __restrict__ bn22, const float* __restrict__ tb2,
    const short* __restrict__ f1,
    const short* __restrict__ gw3b, const float* __restrict__ gb3, const float* __restrict__ bn31,
    const float* __restrict__ adjp, const short* __restrict__ amix,
    const char* __restrict__ zbuf,
    short* __restrict__ f2_out, short* __restrict__ h3_out)
{
    __shared__ char smem[LDS_SZ];
    float* s_cs  = (float*)(smem + TBL_OFF + 1536);

    const int r0 = blockIdx.x * 96;
    const int bstart = (r0 / 6144) * 6144;
    const int bend = bstart + 6144;
    const int tid = threadIdx.x;
    const int l = tid & 63, wid = tid >> 6;
    const int m0w = (wid >> 2) * 48;
    const int lr = l & 15, lk = l >> 4;

    if (tid < 24) s_cs[tid] = adjp[576 + tid];
    // stage h2 halo via DMA (linear dest, pre-swizzled source)
    for (int ck = wid; ck < 36; ck += 8) {
        const int row = ck*4 + (l >> 4);
        const int cg = (l & 15) ^ (row & 7);
        const int gr = r0 - 24 + row;
        const void* gsrc = (gr >= bstart && gr < bend)
            ? (const void*)(h2 + (size_t)gr*128 + cg*8)
            : (const void*)(zbuf + cg*16);
        gload_lds16(gsrc, smem + ck*1024);
    }
    __syncthreads();
    {
        const int n0w = (wid & 3) * 32;
        f32x4 acc[3][2];
        #pragma unroll
        for (int mi = 0; mi < 3; ++mi)
            #pragma unroll
            for (int ni = 0; ni < 2; ++ni) acc[mi][ni] = (f32x4){0.f,0.f,0.f,0.f};
        #pragma unroll
        for (int dt = 0; dt < 3; ++dt) {
            #pragma unroll
            for (int kc = 0; kc < 4; ++kc) {
                short8v bfr[2], afr[3];
                #pragma unroll
                for (int ni = 0; ni < 2; ++ni) {
                    const int n = n0w + ni*16 + lr;
                    bfr[ni] = *(const short8v*)(wt2b + (size_t)n*384 + dt*128 + kc*32 + lk*8);
                }
                #pragma unroll
                for (int mi = 0; mi < 3; ++mi) {
                    const int row = m0w + dt*24 + mi*16 + lr;
                    afr[mi] = *(const short8v*)(smem + row*256 + ((kc*64 + lk*16) ^ ((row&7)<<4)));
                }
                #pragma unroll
                for (int mi = 0; mi < 3; ++mi)
                    #pragma unroll
                    for (int ni = 0; ni < 2; ++ni)
                        acc[mi][ni] = __builtin_amdgcn_mfma_f32_16x16x32_bf16(afr[mi], bfr[ni], acc[mi][ni], 0, 0, 0);
            }
        }
        __syncthreads();
        #pragma unroll
        for (int ni = 0; ni < 2; ++ni) {
            const int o = n0w + ni*16 + lr;
            const float s = bn22[o] * rsqrtf(bn22[384 + o] + 1e-5f);
            const float bias = (bn22[128 + o] - bn22[256 + o]*s) + s*tb2[o];
            #pragma unroll
            for (int mi = 0; mi < 3; ++mi)
                #pragma unroll
                for (int rg = 0; rg < 4; ++rg) {
                    const int rl = m0w + mi*16 + lk*4 + rg;
                    const float res = bf2f(f1[(size_t)(r0 + rl)*128 + o]);
                    const short hv = f2bf(fmaxf(acc[mi][ni][rg] + bias + res, 0.f));
                    *(short*)(smem + o*FT_STRIDE + rl*2) = hv;
                    f2_out[(size_t)(r0 + rl)*128 + o] = hv;
                }
        }
    }
    __syncthreads();
    {
        const int n0w = (wid & 3) * 32;
        f32x4 pacc[3][2];
        #pragma unroll
        for (int mi = 0; mi < 3; ++mi)
            #pragma unroll
            for (int ni = 0; ni < 2; ++ni) pacc[mi][ni] = (f32x4){0.f,0.f,0.f,0.f};
        #pragma unroll
        for (int kc = 0; kc < 3; ++kc) {
            short8v bfr[2], afr[3];
            #pragma unroll
            for (int ni = 0; ni < 2; ++ni) {
                const int ch = n0w + ni*16 + lr;
                bfr[ni] = *(const short8v*)(smem + ch*FT_STRIDE + kc*64 + lk*16);
            }
            #pragma unroll
            for (int mi = 0; mi < 3; ++mi) {
                const int row = m0w + mi*16 + lr;
                afr[mi] = *(const short8v*)(amix + row*96 + kc*32 + lk*8);
            }
            #pragma unroll
            for (int mi = 0; mi < 3; ++mi)
                #pragma unroll
                for (int ni = 0; ni < 2; ++ni)
                    pacc[mi][ni] = __builtin_amdgcn_mfma_f32_16x16x32_bf16(afr[mi], bfr[ni], pacc[mi][ni], 0, 0, 0);
        }
        __syncthreads();
        #pragma unroll
        for (int ni = 0; ni < 2; ++ni) {
            const int ch2 = (n0w + ni*16 + lr) * 2;
            #pragma unroll
            for (int mi = 0; mi < 3; ++mi)
                #pragma unroll
                for (int rg = 0; rg < 4; ++rg) {
                    const int row = m0w + mi*16 + lk*4 + rg;
                    *(short*)(smem + FA_OFF + row*256 + ((ch2 & 0xF0) ^ ((row&7)<<4)) + (ch2 & 14)) =
                        f2bf(pacc[mi][ni][rg]);
                }
        }
    }
    __syncthreads();
    {
        const int n0w = (wid & 3) * 64;
        f32x4 acc[3][4];
        #pragma unroll
        for (int mi = 0; mi < 3; ++mi)
            #pragma unroll
            for (int ni = 0; ni < 4; ++ni) acc[mi][ni] = (f32x4){0.f,0.f,0.f,0.f};
        #pragma unroll
        for (int kc = 0; kc < 4; ++kc) {
            short8v bfr[4], afr[3];
            #pragma unroll
            for (int ni = 0; ni < 4; ++ni) {
                const int n = n0w + ni*16 + lr;
                bfr[ni] = *(const short8v*)(gw3b + (size_t)n*128 + kc*32 + lk*8);
            }
            #pragma unroll
            for (int mi = 0; mi < 3; ++mi) {
                const int row = m0w + mi*16 + lr;
                afr[mi] = *(const short8v*)(smem + FA_OFF + row*256 + ((kc*64 + lk*16) ^ ((row&7)<<4)));
            }
            #pragma unroll
            for (int mi = 0; mi < 3; ++mi)
                #pragma unroll
                for (int ni = 0; ni < 4; ++ni)
                    acc[mi][ni] = __builtin_amdgcn_mfma_f32_16x16x32_bf16(afr[mi], bfr[ni], acc[mi][ni], 0, 0, 0);
        }
        #pragma unroll
        for (int ni = 0; ni < 4; ++ni) {
            const int o = n0w + ni*16 + lr;
            const float s = bn31[o] * rsqrtf(bn31[768 + o] + 1e-5f);
            const float t = bn31[256 + o] - bn31[512 + o]*s;
            const float g = s * gb3[o];
            #pragma unroll
            for (int mi = 0; mi < 3; ++mi)
                #pragma unroll
                for (int rg = 0; rg < 4; ++rg) {
                    const int rl = m0w + mi*16 + lk*4 + rg;
                    h3_out[(size_t)(r0 + rl)*256 + o] = f2bf(fmaxf(acc[mi][ni][rg] + t + g*s_cs[rl % 24], 0.f));
                }
        }
    }
}

// ================================================================ KERNEL 3 (512 thr, 96-row tiles, double-buffered)
__global__ __launch_bounds__(512) void conv3_pool_kernel(
    const short* __restrict__ A, const short* __restrict__ Bw,
    const float* __restrict__ bn, const float* __restrict__ tb,
    const short* __restrict__ f2, const short* __restrict__ rw3b, const float* __restrict__ rb3,
    const char* __restrict__ zbuf, float* __restrict__ pooled)
{
    __shared__ char lds[2 * 36864];          // buf0 + buf1 = 73,728 B -> 2 blocks/CU
    char* buf0 = lds;
    char* buf1 = lds + 36864;
    const int cpx = gridDim.x >> 3;          // gridDim.x % 8 == 0 (64*G)
    const int bid = blockIdx.x;
    const int tile = (bid % 8) * cpx + bid / 8;
    const int r0 = tile * 96;
    const int bb = r0 / 6144;
    const int bstart = bb * 6144, bend = bstart + 6144;
    const int tid = threadIdx.x, l = tid & 63, wid = tid >> 6;
    const int m0w = (wid >> 2) * 48;          // 2-way M (48 rows, 3 frags)
    const int n0w = (wid & 3) * 64;           // 4-way N (64 cols, 4 frags)
    const int lr = l & 15, lk = l >> 4;

    f32x4 acc[3][4];
    #pragma unroll
    for (int mi = 0; mi < 3; ++mi)
        #pragma unroll
        for (int ni = 0; ni < 4; ++ni) acc[mi][ni] = (f32x4){0.f,0.f,0.f,0.f};

    // prologue: stage K-half 0 (144 rows x 128 ch) into buf0
    for (int ck = wid; ck < 36; ck += 8) {
        const int row = ck*4 + (l >> 4);
        const int cg = (l & 15) ^ (row & 7);
        const int gr = r0 - 24 + row;
        const void* gsrc = (gr >= bstart && gr < bend)
            ? (const void*)(A + (size_t)gr*256 + cg*8)
            : (const void*)(zbuf + cg*16);
        gload_lds16(gsrc, buf0 + ck*1024);
    }
    __syncthreads();
    // phase 1: issue K-half 1 DMA into buf1, MFMA over buf0
    for (int ck = wid; ck < 36; ck += 8) {
        const int row = ck*4 + (l >> 4);
        const int cg = (l & 15) ^ (row & 7);
        const int gr = r0 - 24 + row;
        const void* gsrc = (gr >= bstart && gr < bend)
            ? (const void*)(A + (size_t)gr*256 + 128 + cg*8)
            : (const void*)(zbuf + cg*16);
        gload_lds16(gsrc, buf1 + ck*1024);
    }
    #pragma unroll
    for (int dt = 0; dt < 3; ++dt) {
        #pragma unroll
        for (int kc = 0; kc < 4; ++kc) {
            short8v bfr[4], afr[3];
            #pragma unroll
            for (int ni = 0; ni < 4; ++ni) {
                const int n = n0w + ni * 16 + lr;
                bfr[ni] = *(const short8v*)(Bw + (size_t)n * 768 + dt * 256 + kc * 32 + lk * 8);
            }
            #pragma unroll
            for (int mi = 0; mi < 3; ++mi) {
                const int row = m0w + dt * 24 + mi * 16 + lr;
                afr[mi] = *(const short8v*)(buf0 + row * 256 + ((kc * 64 + lk * 16) ^ ((row & 7) << 4)));
            }
            #pragma unroll
            for (int mi = 0; mi < 3; ++mi)
                #pragma unroll
                for (int ni = 0; ni < 4; ++ni)
                    acc[mi][ni] = __builtin_amdgcn_mfma_f32_16x16x32_bf16(afr[mi], bfr[ni], acc[mi][ni], 0, 0, 0);
        }
    }
    __syncthreads();
    // phase 2: issue f2 DMA into buf0 (all buf0 reads complete), MFMA over buf1
    for (int ck = wid; ck < 24; ck += 8) {
        const int row = ck*4 + (l >> 4);
        const int cg = (l & 15) ^ (row & 7);
        gload_lds16((const void*)(f2 + (size_t)(r0 + row)*128 + cg*8), buf0 + ck*1024);
    }
    #pragma unroll
    for (int dt = 0; dt < 3; ++dt) {
        #pragma unroll
        for (int kc = 0; kc < 4; ++kc) {
            short8v bfr[4], afr[3];
            #pragma unroll
            for (int ni = 0; ni < 4; ++ni) {
                const int n = n0w + ni * 16 + lr;
                bfr[ni] = *(const short8v*)(Bw + (size_t)n * 768 + dt * 256 + 128 + kc * 32 + lk * 8);
            }
            #pragma unroll
            for (int mi = 0; mi < 3; ++mi) {
                const int row = m0w + dt * 24 + mi * 16 + lr;
                afr[mi] = *(const short8v*)(buf1 + row * 256 + ((kc * 64 + lk * 16) ^ ((row & 7) << 4)));
            }
            #pragma unroll
            for (int mi = 0; mi < 3; ++mi)
                #pragma unroll
                for (int ni = 0; ni < 4; ++ni)
                    acc[mi][ni] = __builtin_amdgcn_mfma_f32_16x16x32_bf16(afr[mi], bfr[ni], acc[mi][ni], 0, 0, 0);
        }
    }
    __syncthreads();
    // phase 3: R3 MFMA from buf0 (f2)
    #pragma unroll
    for (int kc = 0; kc < 4; ++kc) {
        short8v bfr[4], afr[3];
        #pragma unroll
        for (int ni = 0; ni < 4; ++ni) {
            const int n = n0w + ni * 16 + lr;
            bfr[ni] = *(const short8v*)(rw3b + (size_t)n * 128 + kc * 32 + lk * 8);
        }
        #pragma unroll
        for (int mi = 0; mi < 3; ++mi) {
            const int row = m0w + mi * 16 + lr;
            afr[mi] = *(const short8v*)(buf0 + row * 256 + ((kc * 64 + lk * 16) ^ ((row & 7) << 4)));
        }
        #pragma unroll
        for (int mi = 0; mi < 3; ++mi)
            #pragma unroll
            for (int ni = 0; ni < 4; ++ni)
                acc[mi][ni] = __builtin_amdgcn_mfma_f32_16x16x32_bf16(afr[mi], bfr[ni], acc[mi][ni], 0, 0, 0);
    }

    float psum[4] = {0.f, 0.f, 0.f, 0.f};
    #pragma unroll
    for (int ni = 0; ni < 4; ++ni) {
        const int o = n0w + ni * 16 + lr;
        const float s = bn[o] * rsqrtf(bn[768 + o] + 1e-5f);
        const float t = bn[256 + o] - bn[512 + o] * s;
        const float bias = s * tb[o] + t + rb3[o];
        #pragma unroll
        for (int mi = 0; mi < 3; ++mi)
            #pragma unroll
            for (int rg = 0; rg < 4; ++rg)
                psum[ni] += fmaxf(acc[mi][ni][rg] + bias, 0.f);
    }
    #pragma unroll
    for (int ni = 0; ni < 4; ++ni) {
        float v = psum[ni];
        v += __shfl_xor(v, 16);
        v += __shfl_xor(v, 32);
        if (l < 16) atomicAdd(pooled + (size_t)bb * 256 + (n0w + ni * 16 + l), v);
    }
}

// ---------------------------------------------------------------- head
__global__ __launch_bounds__(256) void head_kernel(const float* __restrict__ pooled_sums,
    const float* __restrict__ ow, const float* __restrict__ ob, float* __restrict__ outp) {
    __shared__ float pooled[256];
    const int b = blockIdx.x, tid = threadIdx.x;
    pooled[tid] = pooled_sums[(size_t)b*256 + tid] * (1.f/6144.f);
    __syncthreads();
    for (int rep = 0; rep < 2; ++rep) {
        const int oo = rep*256 + tid;
        float a = ob[oo];
        const float4* wr = (const float4*)(ow + (size_t)oo*256);
        for (int c4 = 0; c4 < 64; ++c4) {
            const float4 w = wr[c4];
            const float4 p = *(const float4*)&pooled[c4*4];
            a += w.x*p.x + w.y*p.y + w.z*p.z + w.w*p.w;
        }
        outp[(size_t)b*512 + oo] = a;
    }
}

// ---------------------------------------------------------------- launch
extern "C" void kernel_launch(void* const* d_in, const int* in_sizes, int n_in,
                              void* d_out, int out_size, void* d_ws, size_t ws_size,
                              hipStream_t stream)
{
    const float* x        = (const float*)d_in[0];
    const float* b1_gcn_w = (const float*)d_in[1];
    const float* b1_gcn_b = (const float*)d_in[2];
    const float* b1_bn1   = (const float*)d_in[3];
    const float* b1_tcn_w = (const float*)d_in[4];
    const float* b1_tcn_b = (const float*)d_in[5];
    const float* b1_bn2   = (const float*)d_in[6];
    const float* b1_res_w = (const float*)d_in[7];
    const float* b1_res_b = (const float*)d_in[8];
    const float* b2_gcn_w = (const float*)d_in[9];
    const float* b2_gcn_b = (const float*)d_in[10];
    const float* b2_bn1   = (const float*)d_in[11];
    const float* b2_tcn_w = (const float*)d_in[12];
    const float* b2_tcn_b = (const float*)d_in[13];
    const float* b2_bn2   = (const float*)d_in[14];
    const float* b3_gcn_w = (const float*)d_in[15];
    const float* b3_gcn_b = (const float*)d_in[16];
    const float* b3_bn1   = (const float*)d_in[17];
    const float* b3_tcn_w = (const float*)d_in[18];
    const float* b3_tcn_b = (const float*)d_in[19];
    const float* b3_bn2   = (const float*)d_in[20];
    const float* b3_res_w = (const float*)d_in[21];
    const float* b3_res_b = (const float*)d_in[22];
    const float* out_w    = (const float*)d_in[23];
    const float* out_b    = (const float*)d_in[24];

    // ---- fixed workspace carve
    char* w = (char*)d_ws;
    float* adjp = (float*)w;   w += 4096;
    short* wt1b = (short*)w;   w += 98304;
    short* wt2b = (short*)w;   w += 98304;
    short* wt3b = (short*)w;   w += 393216;
    short* gw2b = (short*)w;   w += 32768;
    short* gw3b = (short*)w;   w += 65536;
    short* rw3b = (short*)w;   w += 65536;
    short* amixb = (short*)w;  w += 18432;
    short* gw1b = (short*)w;   w += 4096;
    short* rw1b = (short*)w;   w += 4096;
    float* pooled = (float*)w; w += 32768;
    char* zbuf = w;            w += 1024;           // zero page for OOB halo DMA
    const size_t fixed = (size_t)(w - (char*)d_ws);

    // ---- adaptive batch-group: per-G bytes = 6144 * (256+256+512) = 6,291,456
    int G = 1;
    {
        const int tiers[6] = {32, 16, 8, 4, 2, 1};
        for (int ti = 0; ti < 6; ++ti) {
            const size_t need = fixed + (size_t)tiers[ti] * 6291456ull;
            if (need <= ws_size) { G = tiers[ti]; break; }
        }
    }
    const size_t MG = (size_t)G * 6144;

    short* f1 = (short*)w;           // MG*128  (also serves as f2 after block2)
    short* h2 = f1 + MG*128;         // MG*128
    short* h3 = h2 + MG*128;         // MG*256
    short* f2 = f1;                  // alias

    hipMemsetAsync(pooled, 0, 32768 + 1024, stream);  // pooled + zbuf (adjacent)
    adj_init_kernel<<<1, 256, 0, stream>>>(adjp, amixb);
    prep_kernel<<<1488, 256, 0, stream>>>(b1_tcn_w, b1_bn2, b2_tcn_w, b2_bn2, b3_tcn_w, b3_bn2,
                                          b2_gcn_w, b2_bn1, b3_gcn_w, b3_bn1, b3_res_w,
                                          b1_gcn_w, b1_bn1, b1_res_w,
                                          wt1b, wt2b, wt3b, gw2b, gw3b, rw3b, gw1b, rw1b);

    for (int b0 = 0; b0 < B_; b0 += G) {
        block1_kernel<<<64*G, 512, 0, stream>>>(
            x + (size_t)b0*6144*3,
            gw1b, b1_gcn_b, b1_bn1, rw1b, b1_res_b,
            b1_bn2, b1_tcn_b, wt1b,
            gw2b, b2_gcn_b, b2_bn1, adjp, amixb, f1, h2);
        block2_kernel<<<64*G, 512, 0, stream>>>(
            h2, wt2b, b2_bn2, b2_tcn_b, f1,
            gw3b, b3_gcn_b, b3_bn1, adjp, amixb, zbuf, f2, h3);
        conv3_pool_kernel<<<64*G, 512, 0, stream>>>(
            h3, wt3b, b3_bn2, b3_tcn_b, f2, rw3b, b3_res_b, zbuf, pooled + (size_t)b0*256);
    }

    head_kernel<<<B_, 256, 0, stream>>>(pooled, out_w, out_b, (float*)d_out);
}

// Round 15
// 409.307 us; speedup vs baseline: 1.2119x; 1.2119x over previous
//
#include <hip/hip_runtime.h>
#include <math.h>

#define J_ 24
#define T_ 256
#define B_ 32

typedef short short8v __attribute__((ext_vector_type(8)));   // 8 x bf16 (4 VGPR)
typedef float f32x4  __attribute__((ext_vector_type(4)));    // MFMA acc

__device__ __forceinline__ short f2bf(float f) {
    unsigned u = __float_as_uint(f);
    u += 0x7fffu + ((u >> 16) & 1u);          // round-to-nearest-even
    return (short)(u >> 16);
}
__device__ __forceinline__ float bf2f(short s) {
    return __uint_as_float(((unsigned)(unsigned short)s) << 16);
}

// direct global->LDS DMA: dest = wave-uniform base + lane*16 (linear), source per-lane
__device__ __forceinline__ void gload_lds16(const void* gsrc, void* ldst) {
    __builtin_amdgcn_global_load_lds(
        (const __attribute__((address_space(1))) void*)gsrc,
        (__attribute__((address_space(3))) void*)ldst, 16, 0, 0);
}

__device__ __constant__ int d_parent[24] = {-1,0,0,0,1,2,3,4,5,6,7,8,9,9,9,12,13,14,16,17,18,19,20,21};

// ---------------------------------------------------------------- adjacency tables
__global__ void adj_init_kernel(float* __restrict__ adj_out, short* __restrict__ amix) {
    __shared__ float s_adj[576];
    const int tid = threadIdx.x;
    for (int i = tid; i < 576; i += 256) {
        const int j = i / 24, k = i % 24;
        float a = (j == k || d_parent[k] == j || d_parent[j] == k) ? 1.f : 0.f;
        float d = 0.f;
        for (int kk = 0; kk < 24; ++kk)
            d += (j == kk || d_parent[kk] == j || d_parent[j] == kk) ? 1.f : 0.f;
        const float v = a / fmaxf(d, 1.f);
        s_adj[i] = v;
        adj_out[i] = v;
    }
    __syncthreads();
    if (tid < 24) {
        float cs = 0.f;
        for (int j = 0; j < 24; ++j) cs += s_adj[j*24 + tid];
        adj_out[576 + tid] = cs;
        int n = 0;
        for (int j = 0; j < 24; ++j) {
            const float w = s_adj[j*24 + tid];
            if (w != 0.f && n < 8) {
                adj_out[600 + tid*8 + n] = w;
                adj_out[792 + tid*8 + n] = (float)j;
                ++n;
            }
        }
        for (; n < 8; ++n) { adj_out[600 + tid*8 + n] = 0.f; adj_out[792 + tid*8 + n] = 0.f; }
    }
    __syncthreads();
    for (int i = tid; i < 96*96; i += 256) {
        const int r = i / 96, j = i % 96;
        float v = 0.f;
        if (r / 24 == j / 24) v = s_adj[(j % 24) * 24 + (r % 24)];
        amix[i] = f2bf(v);
    }
}

// ---------------------------------------------------------------- fused weight prep
__global__ __launch_bounds__(256) void prep_kernel(
    const float* __restrict__ w1t, const float* __restrict__ bn1_2,
    const float* __restrict__ w2t, const float* __restrict__ bn2_2,
    const float* __restrict__ w3t, const float* __restrict__ bn3_2,
    const float* __restrict__ g2w, const float* __restrict__ bn2_1,
    const float* __restrict__ g3w, const float* __restrict__ bn3_1,
    const float* __restrict__ r3w,
    const float* __restrict__ g1w, const float* __restrict__ bn1_1,
    const float* __restrict__ r1w,
    short* __restrict__ wt1b, short* __restrict__ wt2b, short* __restrict__ wt3b,
    short* __restrict__ gw2b, short* __restrict__ gw3b, short* __restrict__ rw3b,
    short* __restrict__ gw1b, short* __restrict__ rw1b)
{
    const int i = blockIdx.x * 256 + threadIdx.x;
    if (i < 49152) {
        const int o = i / 384, r = i % 384, dt = r / 128, c = r % 128;
        const float s = bn1_2[o] * rsqrtf(bn1_2[384 + o] + 1e-5f);
        wt1b[i] = f2bf(s * w1t[(o*128 + c)*3 + dt]);
    } else if (i < 98304) {
        const int j = i - 49152;
        const int o = j / 384, r = j % 384, dt = r / 128, c = r % 128;
        const float s = bn2_2[o] * rsqrtf(bn2_2[384 + o] + 1e-5f);
        wt2b[j] = f2bf(s * w2t[(o*128 + c)*3 + dt]);
    } else if (i < 294912) {
        const int j = i - 98304;
        const int o = j / 768, r = j % 768, dt = r / 256, c = r % 256;
        const float s = bn3_2[o] * rsqrtf(bn3_2[768 + o] + 1e-5f);
        wt3b[j] = f2bf(s * w3t[(o*256 + c)*3 + dt]);
    } else if (i < 311296) {
        const int j = i - 294912;
        const int o = j / 128;
        const float s = bn2_1[o] * rsqrtf(bn2_1[384 + o] + 1e-5f);
        gw2b[j] = f2bf(s * g2w[j]);
    } else if (i < 344064) {
        const int j = i - 311296;
        const int o = j / 128;
        const float s = bn3_1[o] * rsqrtf(bn3_1[768 + o] + 1e-5f);
        gw3b[j] = f2bf(s * g3w[j]);
    } else if (i < 376832) {
        const int j = i - 344064;
        rw3b[j] = f2bf(r3w[j]);
    } else if (i < 378880) {
        const int j = i - 376832;
        const int o = j / 8, c = j & 7;
        const float s = bn1_1[o] * rsqrtf(bn1_1[384 + o] + 1e-5f);
        gw1b[j] = (c < 6) ? f2bf(s * g1w[o*6 + c]) : (short)0;
    } else if (i < 380928) {
        const int j = i - 378880;
        const int o = j / 8, c = j & 7;
        rw1b[j] = (c < 6) ? f2bf(r1w[o*6 + c]) : (short)0;
    }
}

// LDS layout (block1/block2), 52,832 B
#define LDS_SZ   52832
#define FA_OFF   26624
#define FT_STRIDE 208
#define X6B_OFF  40320
#define XA6B_OFF 44928
#define TBL_OFF  51200

// ================================================================ KERNEL 1 (512 thr, XCD-chunked tiles)
__global__ __launch_bounds__(512) void block1_kernel(
    const float* __restrict__ x,
    const short* __restrict__ gw1b, const float* __restrict__ gb1, const float* __restrict__ bn1,
    const short* __restrict__ rw1b, const float* __restrict__ rb1,
    const float* __restrict__ bn12, const float* __restrict__ tb1, const short* __restrict__ wt1b,
    const short* __restrict__ gw2b, const float* __restrict__ gb2, const float* __restrict__ bn21,
    const float* __restrict__ adjp, const short* __restrict__ amix,
    short* __restrict__ f1_out, short* __restrict__ h2_out)
{
    __shared__ char smem[LDS_SZ];
    short* s_x6b  = (short*)(smem + X6B_OFF);
    short* s_xa6b = (short*)(smem + XA6B_OFF);
    float* s_cw  = (float*)(smem + TBL_OFF);
    int*   s_ci  = (int*)  (smem + TBL_OFF + 768);
    float* s_cs  = (float*)(smem + TBL_OFF + 1536);

    const int cpx = gridDim.x >> 3;
    const int tile = (blockIdx.x % 8) * cpx + blockIdx.x / 8;
    const int r0 = tile * 96;
    const int bstart = (r0 / 6144) * 6144;
    const int bend = bstart + 6144;
    const int tid = threadIdx.x;
    const int l = tid & 63, wid = tid >> 6;
    const int m0w = (wid >> 2) * 48;
    const int n0w = (wid & 3) * 32;
    const int lr = l & 15, lk = l >> 4;
    const short8v z8 = {0,0,0,0,0,0,0,0};

    if (tid < 192) { s_cw[tid] = adjp[600 + tid]; s_ci[tid] = (int)adjp[792 + tid]; }
    else if (tid < 216) s_cs[tid - 192] = adjp[576 + (tid - 192)];
    // phase A: rot6d -> x6bf [144][8] bf16
    if (tid < 144) {
        const int gr = r0 - 24 + tid;
        short8v v = z8;
        if (gr >= bstart && gr < bend) {
            const float ax = x[gr*3+0], ay = x[gr*3+1], az = x[gr*3+2];
            const float angle = sqrtf(ax*ax + ay*ay + az*az);
            const float inv = 1.f / (angle + 1e-8f);
            const float ux = ax*inv, uy = ay*inv, uz = az*inv;
            const float c = cosf(angle), s = sinf(angle), omc = 1.f - c;
            v[0] = f2bf(c + omc*ux*ux);   v[1] = f2bf(omc*ux*uy - s*uz);
            v[2] = f2bf(omc*uy*ux + s*uz); v[3] = f2bf(c + omc*uy*uy);
            v[4] = f2bf(omc*uz*ux - s*uy); v[5] = f2bf(omc*uz*uy + s*ux);
        }
        *(short8v*)(s_x6b + tid*8) = v;
    }
    __syncthreads();
    // phase B: premix6 (CSR)
    if (tid < 144) {
        const int k = tid % 24, sl = (tid / 24) * 24;
        float a[6] = {0,0,0,0,0,0};
        #pragma unroll
        for (int u = 0; u < 8; ++u) {
            const float wgt = s_cw[k*8+u];
            const short8v v = *(const short8v*)(s_x6b + (sl + s_ci[k*8+u])*8);
            #pragma unroll
            for (int e = 0; e < 6; ++e) a[e] = fmaf(wgt, bf2f(v[e]), a[e]);
        }
        short8v o8 = z8;
        #pragma unroll
        for (int e = 0; e < 6; ++e) o8[e] = f2bf(a[e]);
        *(short8v*)(s_xa6b + tid*8) = o8;
    }
    __syncthreads();
    // phase C: gcn1 via zero-padded MFMA
    {
        const int col = wid*16 + lr;
        short8v bfr = z8;
        if (lk == 0) bfr = *(const short8v*)(gw1b + (size_t)col*8);
        f32x4 cacc[9];
        #pragma unroll
        for (int mi = 0; mi < 9; ++mi) cacc[mi] = (f32x4){0.f,0.f,0.f,0.f};
        #pragma unroll
        for (int mi = 0; mi < 9; ++mi) {
            short8v afr = z8;
            if (lk == 0) afr = *(const short8v*)(s_xa6b + (mi*16 + lr)*8);
            cacc[mi] = __builtin_amdgcn_mfma_f32_16x16x32_bf16(afr, bfr, cacc[mi], 0, 0, 0);
        }
        const float s1 = bn1[col] * rsqrtf(bn1[384 + col] + 1e-5f);
        const float t1 = bn1[128 + col] - bn1[256 + col] * s1;
        const float g1 = s1 * gb1[col];
        const int ch2 = col * 2;
        #pragma unroll
        for (int mi = 0; mi < 9; ++mi)
            #pragma unroll
            for (int rg = 0; rg < 4; ++rg) {
                const int row = mi*16 + lk*4 + rg;
                const int gr = r0 - 24 + row;
                short hv = 0;
                if (gr >= bstart && gr < bend)
                    hv = f2bf(fmaxf(cacc[mi][rg] + t1 + g1*s_cs[row % 24], 0.f));
                *(short*)(smem + row*256 + ((ch2 & 0xF0) ^ ((row&7)<<4)) + (ch2 & 14)) = hv;
            }
    }
    __syncthreads();
    // phase D: conv1 MFMA K=3x128 + R1 MFMA into same acc
    f32x4 acc[3][2];
    #pragma unroll
    for (int mi = 0; mi < 3; ++mi)
        #pragma unroll
        for (int ni = 0; ni < 2; ++ni) acc[mi][ni] = (f32x4){0.f,0.f,0.f,0.f};
    #pragma unroll
    for (int dt = 0; dt < 3; ++dt) {
        #pragma unroll
        for (int kc = 0; kc < 4; ++kc) {
            short8v bfr[2], afr[3];
            #pragma unroll
            for (int ni = 0; ni < 2; ++ni) {
                const int n = n0w + ni*16 + lr;
                bfr[ni] = *(const short8v*)(wt1b + (size_t)n*384 + dt*128 + kc*32 + lk*8);
            }
            #pragma unroll
            for (int mi = 0; mi < 3; ++mi) {
                const int row = m0w + dt*24 + mi*16 + lr;
                afr[mi] = *(const short8v*)(smem + row*256 + ((kc*64 + lk*16) ^ ((row&7)<<4)));
            }
            #pragma unroll
            for (int mi = 0; mi < 3; ++mi)
                #pragma unroll
                for (int ni = 0; ni < 2; ++ni)
                    acc[mi][ni] = __builtin_amdgcn_mfma_f32_16x16x32_bf16(afr[mi], bfr[ni], acc[mi][ni], 0, 0, 0);
        }
    }
    {
        short8v bfr[2], afr[3];
        #pragma unroll
        for (int ni = 0; ni < 2; ++ni) {
            bfr[ni] = z8;
            if (lk == 0) bfr[ni] = *(const short8v*)(rw1b + (size_t)(n0w + ni*16 + lr)*8);
        }
        #pragma unroll
        for (int mi = 0; mi < 3; ++mi) {
            afr[mi] = z8;
            if (lk == 0) afr[mi] = *(const short8v*)(s_x6b + (m0w + mi*16 + lr + 24)*8);
        }
        #pragma unroll
        for (int mi = 0; mi < 3; ++mi)
            #pragma unroll
            for (int ni = 0; ni < 2; ++ni)
                acc[mi][ni] = __builtin_amdgcn_mfma_f32_16x16x32_bf16(afr[mi], bfr[ni], acc[mi][ni], 0, 0, 0);
    }
    __syncthreads();
    // phase E: epilogue -> f1 global + f1T LDS
    #pragma unroll
    for (int ni = 0; ni < 2; ++ni) {
        const int o = n0w + ni*16 + lr;
        const float s2 = bn12[o] * rsqrtf(bn12[384 + o] + 1e-5f);
        const float bias = (bn12[128 + o] - bn12[256 + o]*s2) + s2*tb1[o] + rb1[o];
        #pragma unroll
        for (int mi = 0; mi < 3; ++mi)
            #pragma unroll
            for (int rg = 0; rg < 4; ++rg) {
                const int rl = m0w + mi*16 + lk*4 + rg;
                const short hv = f2bf(fmaxf(acc[mi][ni][rg] + bias, 0.f));
                f1_out[(size_t)(r0 + rl)*128 + o] = hv;
                *(short*)(smem + o*FT_STRIDE + rl*2) = hv;
            }
    }
    __syncthreads();
    // phase F: premix via MFMA  fa = Amix @ f1
    {
        f32x4 pacc[3][2];
        #pragma unroll
        for (int mi = 0; mi < 3; ++mi)
            #pragma unroll
            for (int ni = 0; ni < 2; ++ni) pacc[mi][ni] = (f32x4){0.f,0.f,0.f,0.f};
        #pragma unroll
        for (int kc = 0; kc < 3; ++kc) {
            short8v bfr[2], afr[3];
            #pragma unroll
            for (int ni = 0; ni < 2; ++ni) {
                const int ch = n0w + ni*16 + lr;
                bfr[ni] = *(const short8v*)(smem + ch*FT_STRIDE + kc*64 + lk*16);
            }
            #pragma unroll
            for (int mi = 0; mi < 3; ++mi) {
                const int row = m0w + mi*16 + lr;
                afr[mi] = *(const short8v*)(amix + row*96 + kc*32 + lk*8);
            }
            #pragma unroll
            for (int mi = 0; mi < 3; ++mi)
                #pragma unroll
                for (int ni = 0; ni < 2; ++ni)
                    pacc[mi][ni] = __builtin_amdgcn_mfma_f32_16x16x32_bf16(afr[mi], bfr[ni], pacc[mi][ni], 0, 0, 0);
        }
        __syncthreads();
        #pragma unroll
        for (int ni = 0; ni < 2; ++ni) {
            const int ch2 = (n0w + ni*16 + lr) * 2;
            #pragma unroll
            for (int mi = 0; mi < 3; ++mi)
                #pragma unroll
                for (int rg = 0; rg < 4; ++rg) {
                    const int row = m0w + mi*16 + lk*4 + rg;
                    *(short*)(smem + FA_OFF + row*256 + ((ch2 & 0xF0) ^ ((row&7)<<4)) + (ch2 & 14)) =
                        f2bf(pacc[mi][ni][rg]);
                }
        }
    }
    __syncthreads();
    // phase G: gcn2 MFMA K=128 -> h2
    #pragma unroll
    for (int mi = 0; mi < 3; ++mi)
        #pragma unroll
        for (int ni = 0; ni < 2; ++ni) acc[mi][ni] = (f32x4){0.f,0.f,0.f,0.f};
    #pragma unroll
    for (int kc = 0; kc < 4; ++kc) {
        short8v bfr[2], afr[3];
        #pragma unroll
        for (int ni = 0; ni < 2; ++ni) {
            const int n = n0w + ni*16 + lr;
            bfr[ni] = *(const short8v*)(gw2b + (size_t)n*128 + kc*32 + lk*8);
        }
        #pragma unroll
        for (int mi = 0; mi < 3; ++mi) {
            const int row = m0w + mi*16 + lr;
            afr[mi] = *(const short8v*)(smem + FA_OFF + row*256 + ((kc*64 + lk*16) ^ ((row&7)<<4)));
        }
        #pragma unroll
        for (int mi = 0; mi < 3; ++mi)
            #pragma unroll
            for (int ni = 0; ni < 2; ++ni)
                acc[mi][ni] = __builtin_amdgcn_mfma_f32_16x16x32_bf16(afr[mi], bfr[ni], acc[mi][ni], 0, 0, 0);
    }
    #pragma unroll
    for (int ni = 0; ni < 2; ++ni) {
        const int o = n0w + ni*16 + lr;
        const float s = bn21[o] * rsqrtf(bn21[384 + o] + 1e-5f);
        const float t = bn21[128 + o] - bn21[256 + o]*s;
        const float g = s * gb2[o];
        #pragma unroll
        for (int mi = 0; mi < 3; ++mi)
            #pragma unroll
            for (int rg = 0; rg < 4; ++rg) {
                const int rl = m0w + mi*16 + lk*4 + rg;
                h2_out[(size_t)(r0 + rl)*128 + o] = f2bf(fmaxf(acc[mi][ni][rg] + t + g*s_cs[rl % 24], 0.f));
            }
    }
}

// ================================================================ KERNEL 2 (512 thr, XCD-chunked tiles)
__global__ __launch_bounds__(512) void block2_kernel(
    const short* __restrict__ h2, const short* __restrict__ wt2b,
    const float* __restrict__ bn22, const float* __restrict__ tb2,
    const short* __restrict__ f1,
    const short* __restrict__ gw3b, const float* __restrict__ gb3, const float* __restrict__ bn31,
    const float* __restrict__ adjp, const short* __restrict__ amix,
    const char* __restrict__ zbuf,
    short* __restrict__ f2_out, short* __restrict__ h3_out)
{
    __shared__ char smem[LDS_SZ];
    float* s_cs  = (float*)(smem + TBL_OFF + 1536);

    const int cpx = gridDim.x >> 3;
    const int tile = (blockIdx.x % 8) * cpx + blockIdx.x / 8;
    const int r0 = tile * 96;
    const int bstart = (r0 / 6144) * 6144;
    const int bend = bstart + 6144;
    const int tid = threadIdx.x;
    const int l = tid & 63, wid = tid >> 6;
    const int m0w = (wid >> 2) * 48;
    const int lr = l & 15, lk = l >> 4;

    if (tid < 24) s_cs[tid] = adjp[576 + tid];
    for (int ck = wid; ck < 36; ck += 8) {
        const int row = ck*4 + (l >> 4);
        const int cg = (l & 15) ^ (row & 7);
        const int gr = r0 - 24 + row;
        const void* gsrc = (gr >= bstart && gr < bend)
            ? (const void*)(h2 + (size_t)gr*128 + cg*8)
            : (const void*)(zbuf + cg*16);
        gload_lds16(gsrc, smem + ck*1024);
    }
    __syncthreads();
    {
        const int n0w = (wid & 3) * 32;
        f32x4 acc[3][2];
        #pragma unroll
        for (int mi = 0; mi < 3; ++mi)
            #pragma unroll
            for (int ni = 0; ni < 2; ++ni) acc[mi][ni] = (f32x4){0.f,0.f,0.f,0.f};
        #pragma unroll
        for (int dt = 0; dt < 3; ++dt) {
            #pragma unroll
            for (int kc = 0; kc < 4; ++kc) {
                short8v bfr[2], afr[3];
                #pragma unroll
                for (int ni = 0; ni < 2; ++ni) {
                    const int n = n0w + ni*16 + lr;
                    bfr[ni] = *(const short8v*)(wt2b + (size_t)n*384 + dt*128 + kc*32 + lk*8);
                }
                #pragma unroll
                for (int mi = 0; mi < 3; ++mi) {
                    const int row = m0w + dt*24 + mi*16 + lr;
                    afr[mi] = *(const short8v*)(smem + row*256 + ((kc*64 + lk*16) ^ ((row&7)<<4)));
                }
                #pragma unroll
                for (int mi = 0; mi < 3; ++mi)
                    #pragma unroll
                    for (int ni = 0; ni < 2; ++ni)
                        acc[mi][ni] = __builtin_amdgcn_mfma_f32_16x16x32_bf16(afr[mi], bfr[ni], acc[mi][ni], 0, 0, 0);
            }
        }
        __syncthreads();
        #pragma unroll
        for (int ni = 0; ni < 2; ++ni) {
            const int o = n0w + ni*16 + lr;
            const float s = bn22[o] * rsqrtf(bn22[384 + o] + 1e-5f);
            const float bias = (bn22[128 + o] - bn22[256 + o]*s) + s*tb2[o];
            #pragma unroll
            for (int mi = 0; mi < 3; ++mi)
                #pragma unroll
                for (int rg = 0; rg < 4; ++rg) {
                    const int rl = m0w + mi*16 + lk*4 + rg;
                    const float res = bf2f(f1[(size_t)(r0 + rl)*128 + o]);
                    const short hv = f2bf(fmaxf(acc[mi][ni][rg] + bias + res, 0.f));
                    *(short*)(smem + o*FT_STRIDE + rl*2) = hv;
                    f2_out[(size_t)(r0 + rl)*128 + o] = hv;
                }
        }
    }
    __syncthreads();
    {
        const int n0w = (wid & 3) * 32;
        f32x4 pacc[3][2];
        #pragma unroll
        for (int mi = 0; mi < 3; ++mi)
            #pragma unroll
            for (int ni = 0; ni < 2; ++ni) pacc[mi][ni] = (f32x4){0.f,0.f,0.f,0.f};
        #pragma unroll
        for (int kc = 0; kc < 3; ++kc) {
            short8v bfr[2], afr[3];
            #pragma unroll
            for (int ni = 0; ni < 2; ++ni) {
                const int ch = n0w + ni*16 + lr;
                bfr[ni] = *(const short8v*)(smem + ch*FT_STRIDE + kc*64 + lk*16);
            }
            #pragma unroll
            for (int mi = 0; mi < 3; ++mi) {
                const int row = m0w + mi*16 + lr;
                afr[mi] = *(const short8v*)(amix + row*96 + kc*32 + lk*8);
            }
            #pragma unroll
            for (int mi = 0; mi < 3; ++mi)
                #pragma unroll
                for (int ni = 0; ni < 2; ++ni)
                    pacc[mi][ni] = __builtin_amdgcn_mfma_f32_16x16x32_bf16(afr[mi], bfr[ni], pacc[mi][ni], 0, 0, 0);
        }
        __syncthreads();
        #pragma unroll
        for (int ni = 0; ni < 2; ++ni) {
            const int ch2 = (n0w + ni*16 + lr) * 2;
            #pragma unroll
            for (int mi = 0; mi < 3; ++mi)
                #pragma unroll
                for (int rg = 0; rg < 4; ++rg) {
                    const int row = m0w + mi*16 + lk*4 + rg;
                    *(short*)(smem + FA_OFF + row*256 + ((ch2 & 0xF0) ^ ((row&7)<<4)) + (ch2 & 14)) =
                        f2bf(pacc[mi][ni][rg]);
                }
        }
    }
    __syncthreads();
    {
        const int n0w = (wid & 3) * 64;
        f32x4 acc[3][4];
        #pragma unroll
        for (int mi = 0; mi < 3; ++mi)
            #pragma unroll
            for (int ni = 0; ni < 4; ++ni) acc[mi][ni] = (f32x4){0.f,0.f,0.f,0.f};
        #pragma unroll
        for (int kc = 0; kc < 4; ++kc) {
            short8v bfr[4], afr[3];
            #pragma unroll
            for (int ni = 0; ni < 4; ++ni) {
                const int n = n0w + ni*16 + lr;
                bfr[ni] = *(const short8v*)(gw3b + (size_t)n*128 + kc*32 + lk*8);
            }
            #pragma unroll
            for (int mi = 0; mi < 3; ++mi) {
                const int row = m0w + mi*16 + lr;
                afr[mi] = *(const short8v*)(smem + FA_OFF + row*256 + ((kc*64 + lk*16) ^ ((row&7)<<4)));
            }
            #pragma unroll
            for (int mi = 0; mi < 3; ++mi)
                #pragma unroll
                for (int ni = 0; ni < 4; ++ni)
                    acc[mi][ni] = __builtin_amdgcn_mfma_f32_16x16x32_bf16(afr[mi], bfr[ni], acc[mi][ni], 0, 0, 0);
        }
        #pragma unroll
        for (int ni = 0; ni < 4; ++ni) {
            const int o = n0w + ni*16 + lr;
            const float s = bn31[o] * rsqrtf(bn31[768 + o] + 1e-5f);
            const float t = bn31[256 + o] - bn31[512 + o]*s;
            const float g = s * gb3[o];
            #pragma unroll
            for (int mi = 0; mi < 3; ++mi)
                #pragma unroll
                for (int rg = 0; rg < 4; ++rg) {
                    const int rl = m0w + mi*16 + lk*4 + rg;
                    h3_out[(size_t)(r0 + rl)*256 + o] = f2bf(fmaxf(acc[mi][ni][rg] + t + g*s_cs[rl % 24], 0.f));
                }
        }
    }
}

// ================================================================ KERNEL 3 (512 thr, 192-row tiles)  [round-12 proven]
__global__ __launch_bounds__(512) void conv3_pool_kernel(
    const short* __restrict__ A, const short* __restrict__ Bw,
    const float* __restrict__ bn, const float* __restrict__ tb,
    const short* __restrict__ f2, const short* __restrict__ rw3b, const float* __restrict__ rb3,
    const char* __restrict__ zbuf, float* __restrict__ pooled)
{
    __shared__ char lds[240 * 256];
    const int cpx = gridDim.x >> 3;
    const int bid = blockIdx.x;
    const int tile = (bid % 8) * cpx + bid / 8;
    const int r0 = tile * 192;
    const int bb = r0 / 6144;
    const int bstart = bb * 6144, bend = bstart + 6144;
    const int tid = threadIdx.x, l = tid & 63, wid = tid >> 6;
    const int m0w = (wid >> 2) * 96;
    const int n0w = (wid & 3) * 64;
    const int lr = l & 15, lk = l >> 4;

    f32x4 acc[6][4];
    #pragma unroll
    for (int mi = 0; mi < 6; ++mi)
        #pragma unroll
        for (int ni = 0; ni < 4; ++ni) acc[mi][ni] = (f32x4){0.f,0.f,0.f,0.f};

    for (int p = 0; p < 2; ++p) {
        if (p) __syncthreads();
        for (int ck = wid; ck < 60; ck += 8) {
            const int row = ck*4 + (l >> 4);
            const int cg = (l & 15) ^ (row & 7);
            const int gr = r0 - 24 + row;
            const void* gsrc = (gr >= bstart && gr < bend)
                ? (const void*)(A + (size_t)gr*256 + p*128 + cg*8)
                : (const void*)(zbuf + cg*16);
            gload_lds16(gsrc, lds + ck*1024);
        }
        __syncthreads();
        #pragma unroll
        for (int dt = 0; dt < 3; ++dt) {
            #pragma unroll
            for (int kc = 0; kc < 4; ++kc) {
                short8v bfr[4], afr[6];
                #pragma unroll
                for (int ni = 0; ni < 4; ++ni) {
                    const int n = n0w + ni * 16 + lr;
                    bfr[ni] = *(const short8v*)(Bw + (size_t)n * 768 + dt * 256 + p * 128 + kc * 32 + lk * 8);
                }
                #pragma unroll
                for (int mi = 0; mi < 6; ++mi) {
                    const int row = m0w + dt * 24 + mi * 16 + lr;
                    afr[mi] = *(const short8v*)(lds + row * 256 + ((kc * 64 + lk * 16) ^ ((row & 7) << 4)));
                }
                #pragma unroll
                for (int mi = 0; mi < 6; ++mi)
                    #pragma unroll
                    for (int ni = 0; ni < 4; ++ni)
                        acc[mi][ni] = __builtin_amdgcn_mfma_f32_16x16x32_bf16(afr[mi], bfr[ni], acc[mi][ni], 0, 0, 0);
            }
        }
    }
    __syncthreads();
    for (int ck = wid; ck < 48; ck += 8) {
        const int row = ck*4 + (l >> 4);
        const int cg = (l & 15) ^ (row & 7);
        gload_lds16((const void*)(f2 + (size_t)(r0 + row)*128 + cg*8), lds + ck*1024);
    }
    __syncthreads();
    #pragma unroll
    for (int kc = 0; kc < 4; ++kc) {
        short8v bfr[4], afr[6];
        #pragma unroll
        for (int ni = 0; ni < 4; ++ni) {
            const int n = n0w + ni * 16 + lr;
            bfr[ni] = *(const short8v*)(rw3b + (size_t)n * 128 + kc * 32 + lk * 8);
        }
        #pragma unroll
        for (int mi = 0; mi < 6; ++mi) {
            const int row = m0w + mi * 16 + lr;
            afr[mi] = *(const short8v*)(lds + row * 256 + ((kc * 64 + lk * 16) ^ ((row & 7) << 4)));
        }
        #pragma unroll
        for (int mi = 0; mi < 6; ++mi)
            #pragma unroll
            for (int ni = 0; ni < 4; ++ni)
                acc[mi][ni] = __builtin_amdgcn_mfma_f32_16x16x32_bf16(afr[mi], bfr[ni], acc[mi][ni], 0, 0, 0);
    }

    float psum[4] = {0.f, 0.f, 0.f, 0.f};
    #pragma unroll
    for (int ni = 0; ni < 4; ++ni) {
        const int o = n0w + ni * 16 + lr;
        const float s = bn[o] * rsqrtf(bn[768 + o] + 1e-5f);
        const float t = bn[256 + o] - bn[512 + o] * s;
        const float bias = s * tb[o] + t + rb3[o];
        #pragma unroll
        for (int mi = 0; mi < 6; ++mi)
            #pragma unroll
            for (int rg = 0; rg < 4; ++rg)
                psum[ni] += fmaxf(acc[mi][ni][rg] + bias, 0.f);
    }
    #pragma unroll
    for (int ni = 0; ni < 4; ++ni) {
        float v = psum[ni];
        v += __shfl_xor(v, 16);
        v += __shfl_xor(v, 32);
        if (l < 16) atomicAdd(pooled + (size_t)bb * 256 + (n0w + ni * 16 + l), v);
    }
}

// ---------------------------------------------------------------- head
__global__ __launch_bounds__(256) void head_kernel(const float* __restrict__ pooled_sums,
    const float* __restrict__ ow, const float* __restrict__ ob, float* __restrict__ outp) {
    __shared__ float pooled[256];
    const int b = blockIdx.x, tid = threadIdx.x;
    pooled[tid] = pooled_sums[(size_t)b*256 + tid] * (1.f/6144.f);
    __syncthreads();
    for (int rep = 0; rep < 2; ++rep) {
        const int oo = rep*256 + tid;
        float a = ob[oo];
        const float4* wr = (const float4*)(ow + (size_t)oo*256);
        for (int c4 = 0; c4 < 64; ++c4) {
            const float4 w = wr[c4];
            const float4 p = *(const float4*)&pooled[c4*4];
            a += w.x*p.x + w.y*p.y + w.z*p.z + w.w*p.w;
        }
        outp[(size_t)b*512 + oo] = a;
    }
}

// ---------------------------------------------------------------- launch
extern "C" void kernel_launch(void* const* d_in, const int* in_sizes, int n_in,
                              void* d_out, int out_size, void* d_ws, size_t ws_size,
                              hipStream_t stream)
{
    const float* x        = (const float*)d_in[0];
    const float* b1_gcn_w = (const float*)d_in[1];
    const float* b1_gcn_b = (const float*)d_in[2];
    const float* b1_bn1   = (const float*)d_in[3];
    const float* b1_tcn_w = (const float*)d_in[4];
    const float* b1_tcn_b = (const float*)d_in[5];
    const float* b1_bn2   = (const float*)d_in[6];
    const float* b1_res_w = (const float*)d_in[7];
    const float* b1_res_b = (const float*)d_in[8];
    const float* b2_gcn_w = (const float*)d_in[9];
    const float* b2_gcn_b = (const float*)d_in[10];
    const float* b2_bn1   = (const float*)d_in[11];
    const float* b2_tcn_w = (const float*)d_in[12];
    const float* b2_tcn_b = (const float*)d_in[13];
    const float* b2_bn2   = (const float*)d_in[14];
    const float* b3_gcn_w = (const float*)d_in[15];
    const float* b3_gcn_b = (const float*)d_in[16];
    const float* b3_bn1   = (const float*)d_in[17];
    const float* b3_tcn_w = (const float*)d_in[18];
    const float* b3_tcn_b = (const float*)d_in[19];
    const float* b3_bn2   = (const float*)d_in[20];
    const float* b3_res_w = (const float*)d_in[21];
    const float* b3_res_b = (const float*)d_in[22];
    const float* out_w    = (const float*)d_in[23];
    const float* out_b    = (const float*)d_in[24];

    // ---- fixed workspace carve
    char* w = (char*)d_ws;
    float* adjp = (float*)w;   w += 4096;
    short* wt1b = (short*)w;   w += 98304;
    short* wt2b = (short*)w;   w += 98304;
    short* wt3b = (short*)w;   w += 393216;
    short* gw2b = (short*)w;   w += 32768;
    short* gw3b = (short*)w;   w += 65536;
    short* rw3b = (short*)w;   w += 65536;
    short* amixb = (short*)w;  w += 18432;
    short* gw1b = (short*)w;   w += 4096;
    short* rw1b = (short*)w;   w += 4096;
    float* pooled = (float*)w; w += 32768;
    char* zbuf = w;            w += 1024;           // zero page for OOB halo DMA
    const size_t fixed = (size_t)(w - (char*)d_ws);

    // ---- adaptive batch-group: per-G bytes = 6144 * (256+256+512) = 6,291,456
    int G = 1;
    {
        const int tiers[6] = {32, 16, 8, 4, 2, 1};
        for (int ti = 0; ti < 6; ++ti) {
            const size_t need = fixed + (size_t)tiers[ti] * 6291456ull;
            if (need <= ws_size) { G = tiers[ti]; break; }
        }
    }
    const size_t MG = (size_t)G * 6144;

    short* f1 = (short*)w;           // MG*128  (also serves as f2 after block2)
    short* h2 = f1 + MG*128;         // MG*128
    short* h3 = h2 + MG*128;         // MG*256
    short* f2 = f1;                  // alias

    hipMemsetAsync(pooled, 0, 32768 + 1024, stream);  // pooled + zbuf (adjacent)
    adj_init_kernel<<<1, 256, 0, stream>>>(adjp, amixb);
    prep_kernel<<<1488, 256, 0, stream>>>(b1_tcn_w, b1_bn2, b2_tcn_w, b2_bn2, b3_tcn_w, b3_bn2,
                                          b2_gcn_w, b2_bn1, b3_gcn_w, b3_bn1, b3_res_w,
                                          b1_gcn_w, b1_bn1, b1_res_w,
                                          wt1b, wt2b, wt3b, gw2b, gw3b, rw3b, gw1b, rw1b);

    for (int b0 = 0; b0 < B_; b0 += G) {
        block1_kernel<<<64*G, 512, 0, stream>>>(
            x + (size_t)b0*6144*3,
            gw1b, b1_gcn_b, b1_bn1, rw1b, b1_res_b,
            b1_bn2, b1_tcn_b, wt1b,
            gw2b, b2_gcn_b, b2_bn1, adjp, amixb, f1, h2);
        block2_kernel<<<64*G, 512, 0, stream>>>(
            h2, wt2b, b2_bn2, b2_tcn_b, f1,
            gw3b, b3_gcn_b, b3_bn1, adjp, amixb, zbuf, f2, h3);
        conv3_pool_kernel<<<32*G, 512, 0, stream>>>(
            h3, wt3b, b3_bn2, b3_tcn_b, f2, rw3b, b3_res_b, zbuf, pooled + (size_t)b0*256);
    }

    head_kernel<<<B_, 256, 0, stream>>>(pooled, out_w, out_b, (float*)d_out);
}

// Round 16
// 408.852 us; speedup vs baseline: 1.2132x; 1.0011x over previous
//
#include <hip/hip_runtime.h>
#include <math.h>

#define J_ 24
#define T_ 256
#define B_ 32

typedef short short8v __attribute__((ext_vector_type(8)));   // 8 x bf16 (4 VGPR)
typedef float f32x4  __attribute__((ext_vector_type(4)));    // MFMA acc

__device__ __forceinline__ short f2bf(float f) {
    unsigned u = __float_as_uint(f);
    u += 0x7fffu + ((u >> 16) & 1u);          // round-to-nearest-even
    return (short)(u >> 16);
}
__device__ __forceinline__ float bf2f(short s) {
    return __uint_as_float(((unsigned)(unsigned short)s) << 16);
}

// direct global->LDS DMA: dest = wave-uniform base + lane*16 (linear), source per-lane
__device__ __forceinline__ void gload_lds16(const void* gsrc, void* ldst) {
    __builtin_amdgcn_global_load_lds(
        (const __attribute__((address_space(1))) void*)gsrc,
        (__attribute__((address_space(3))) void*)ldst, 16, 0, 0);
}

__device__ __constant__ int d_parent[24] = {-1,0,0,0,1,2,3,4,5,6,7,8,9,9,9,12,13,14,16,17,18,19,20,21};

// ---------------------------------------------------------------- adjacency tables
__global__ void adj_init_kernel(float* __restrict__ adj_out, short* __restrict__ amix) {
    __shared__ float s_adj[576];
    const int tid = threadIdx.x;
    for (int i = tid; i < 576; i += 256) {
        const int j = i / 24, k = i % 24;
        float a = (j == k || d_parent[k] == j || d_parent[j] == k) ? 1.f : 0.f;
        float d = 0.f;
        for (int kk = 0; kk < 24; ++kk)
            d += (j == kk || d_parent[kk] == j || d_parent[j] == kk) ? 1.f : 0.f;
        const float v = a / fmaxf(d, 1.f);
        s_adj[i] = v;
        adj_out[i] = v;
    }
    __syncthreads();
    if (tid < 24) {
        float cs = 0.f;
        for (int j = 0; j < 24; ++j) cs += s_adj[j*24 + tid];
        adj_out[576 + tid] = cs;
        int n = 0;
        for (int j = 0; j < 24; ++j) {
            const float w = s_adj[j*24 + tid];
            if (w != 0.f && n < 8) {
                adj_out[600 + tid*8 + n] = w;
                adj_out[792 + tid*8 + n] = (float)j;
                ++n;
            }
        }
        for (; n < 8; ++n) { adj_out[600 + tid*8 + n] = 0.f; adj_out[792 + tid*8 + n] = 0.f; }
    }
    __syncthreads();
    for (int i = tid; i < 96*96; i += 256) {
        const int r = i / 96, j = i % 96;
        float v = 0.f;
        if (r / 24 == j / 24) v = s_adj[(j % 24) * 24 + (r % 24)];
        amix[i] = f2bf(v);
    }
}

// ---------------------------------------------------------------- fused weight prep
__global__ __launch_bounds__(256) void prep_kernel(
    const float* __restrict__ w1t, const float* __restrict__ bn1_2,
    const float* __restrict__ w2t, const float* __restrict__ bn2_2,
    const float* __restrict__ w3t, const float* __restrict__ bn3_2,
    const float* __restrict__ g2w, const float* __restrict__ bn2_1,
    const float* __restrict__ g3w, const float* __restrict__ bn3_1,
    const float* __restrict__ r3w,
    const float* __restrict__ g1w, const float* __restrict__ bn1_1,
    const float* __restrict__ r1w,
    short* __restrict__ wt1b, short* __restrict__ wt2b, short* __restrict__ wt3b,
    short* __restrict__ gw2b, short* __restrict__ gw3b, short* __restrict__ rw3b,
    short* __restrict__ gw1b, short* __restrict__ rw1b)
{
    const int i = blockIdx.x * 256 + threadIdx.x;
    if (i < 49152) {
        const int o = i / 384, r = i % 384, dt = r / 128, c = r % 128;
        const float s = bn1_2[o] * rsqrtf(bn1_2[384 + o] + 1e-5f);
        wt1b[i] = f2bf(s * w1t[(o*128 + c)*3 + dt]);
    } else if (i < 98304) {
        const int j = i - 49152;
        const int o = j / 384, r = j % 384, dt = r / 128, c = r % 128;
        const float s = bn2_2[o] * rsqrtf(bn2_2[384 + o] + 1e-5f);
        wt2b[j] = f2bf(s * w2t[(o*128 + c)*3 + dt]);
    } else if (i < 294912) {
        const int j = i - 98304;
        const int o = j / 768, r = j % 768, dt = r / 256, c = r % 256;
        const float s = bn3_2[o] * rsqrtf(bn3_2[768 + o] + 1e-5f);
        wt3b[j] = f2bf(s * w3t[(o*256 + c)*3 + dt]);
    } else if (i < 311296) {
        const int j = i - 294912;
        const int o = j / 128;
        const float s = bn2_1[o] * rsqrtf(bn2_1[384 + o] + 1e-5f);
        gw2b[j] = f2bf(s * g2w[j]);
    } else if (i < 344064) {
        const int j = i - 311296;
        const int o = j / 128;
        const float s = bn3_1[o] * rsqrtf(bn3_1[768 + o] + 1e-5f);
        gw3b[j] = f2bf(s * g3w[j]);
    } else if (i < 376832) {
        const int j = i - 344064;
        rw3b[j] = f2bf(r3w[j]);
    } else if (i < 378880) {
        const int j = i - 376832;
        const int o = j / 8, c = j & 7;
        const float s = bn1_1[o] * rsqrtf(bn1_1[384 + o] + 1e-5f);
        gw1b[j] = (c < 6) ? f2bf(s * g1w[o*6 + c]) : (short)0;
    } else if (i < 380928) {
        const int j = i - 378880;
        const int o = j / 8, c = j & 7;
        rw1b[j] = (c < 6) ? f2bf(r1w[o*6 + c]) : (short)0;
    }
}

// LDS layout (block1/block2), 52,832 B
#define LDS_SZ   52832
#define FA_OFF   26624
#define FT_STRIDE 208
#define X6B_OFF  40320
#define XA6B_OFF 44928
#define TBL_OFF  51200

// ================================================================ KERNEL 1 (512 thr, XCD-chunked tiles)
__global__ __launch_bounds__(512) void block1_kernel(
    const float* __restrict__ x,
    const short* __restrict__ gw1b, const float* __restrict__ gb1, const float* __restrict__ bn1,
    const short* __restrict__ rw1b, const float* __restrict__ rb1,
    const float* __restrict__ bn12, const float* __restrict__ tb1, const short* __restrict__ wt1b,
    const short* __restrict__ gw2b, const float* __restrict__ gb2, const float* __restrict__ bn21,
    const float* __restrict__ adjp, const short* __restrict__ amix,
    short* __restrict__ f1_out, short* __restrict__ h2_out)
{
    __shared__ char smem[LDS_SZ];
    short* s_x6b  = (short*)(smem + X6B_OFF);
    short* s_xa6b = (short*)(smem + XA6B_OFF);
    float* s_cw  = (float*)(smem + TBL_OFF);
    int*   s_ci  = (int*)  (smem + TBL_OFF + 768);
    float* s_cs  = (float*)(smem + TBL_OFF + 1536);

    const int cpx = gridDim.x >> 3;
    const int tile = (blockIdx.x % 8) * cpx + blockIdx.x / 8;
    const int r0 = tile * 96;
    const int bstart = (r0 / 6144) * 6144;
    const int bend = bstart + 6144;
    const int tid = threadIdx.x;
    const int l = tid & 63, wid = tid >> 6;
    const int m0w = (wid >> 2) * 48;
    const int n0w = (wid & 3) * 32;
    const int lr = l & 15, lk = l >> 4;
    const short8v z8 = {0,0,0,0,0,0,0,0};

    if (tid < 192) { s_cw[tid] = adjp[600 + tid]; s_ci[tid] = (int)adjp[792 + tid]; }
    else if (tid < 216) s_cs[tid - 192] = adjp[576 + (tid - 192)];
    // phase A: rot6d -> x6bf [144][8] bf16
    if (tid < 144) {
        const int gr = r0 - 24 + tid;
        short8v v = z8;
        if (gr >= bstart && gr < bend) {
            const float ax = x[gr*3+0], ay = x[gr*3+1], az = x[gr*3+2];
            const float angle = sqrtf(ax*ax + ay*ay + az*az);
            const float inv = 1.f / (angle + 1e-8f);
            const float ux = ax*inv, uy = ay*inv, uz = az*inv;
            const float c = cosf(angle), s = sinf(angle), omc = 1.f - c;
            v[0] = f2bf(c + omc*ux*ux);   v[1] = f2bf(omc*ux*uy - s*uz);
            v[2] = f2bf(omc*uy*ux + s*uz); v[3] = f2bf(c + omc*uy*uy);
            v[4] = f2bf(omc*uz*ux - s*uy); v[5] = f2bf(omc*uz*uy + s*ux);
        }
        *(short8v*)(s_x6b + tid*8) = v;
    }
    __syncthreads();
    // phase B: premix6 (CSR)
    if (tid < 144) {
        const int k = tid % 24, sl = (tid / 24) * 24;
        float a[6] = {0,0,0,0,0,0};
        #pragma unroll
        for (int u = 0; u < 8; ++u) {
            const float wgt = s_cw[k*8+u];
            const short8v v = *(const short8v*)(s_x6b + (sl + s_ci[k*8+u])*8);
            #pragma unroll
            for (int e = 0; e < 6; ++e) a[e] = fmaf(wgt, bf2f(v[e]), a[e]);
        }
        short8v o8 = z8;
        #pragma unroll
        for (int e = 0; e < 6; ++e) o8[e] = f2bf(a[e]);
        *(short8v*)(s_xa6b + tid*8) = o8;
    }
    __syncthreads();
    // phase C: gcn1 via zero-padded MFMA
    {
        const int col = wid*16 + lr;
        short8v bfr = z8;
        if (lk == 0) bfr = *(const short8v*)(gw1b + (size_t)col*8);
        f32x4 cacc[9];
        #pragma unroll
        for (int mi = 0; mi < 9; ++mi) cacc[mi] = (f32x4){0.f,0.f,0.f,0.f};
        #pragma unroll
        for (int mi = 0; mi < 9; ++mi) {
            short8v afr = z8;
            if (lk == 0) afr = *(const short8v*)(s_xa6b + (mi*16 + lr)*8);
            cacc[mi] = __builtin_amdgcn_mfma_f32_16x16x32_bf16(afr, bfr, cacc[mi], 0, 0, 0);
        }
        const float s1 = bn1[col] * rsqrtf(bn1[384 + col] + 1e-5f);
        const float t1 = bn1[128 + col] - bn1[256 + col] * s1;
        const float g1 = s1 * gb1[col];
        const int ch2 = col * 2;
        #pragma unroll
        for (int mi = 0; mi < 9; ++mi)
            #pragma unroll
            for (int rg = 0; rg < 4; ++rg) {
                const int row = mi*16 + lk*4 + rg;
                const int gr = r0 - 24 + row;
                short hv = 0;
                if (gr >= bstart && gr < bend)
                    hv = f2bf(fmaxf(cacc[mi][rg] + t1 + g1*s_cs[row % 24], 0.f));
                *(short*)(smem + row*256 + ((ch2 & 0xF0) ^ ((row&7)<<4)) + (ch2 & 14)) = hv;
            }
    }
    __syncthreads();
    // phase D: conv1 MFMA K=3x128 + R1 MFMA into same acc
    f32x4 acc[3][2];
    #pragma unroll
    for (int mi = 0; mi < 3; ++mi)
        #pragma unroll
        for (int ni = 0; ni < 2; ++ni) acc[mi][ni] = (f32x4){0.f,0.f,0.f,0.f};
    #pragma unroll
    for (int dt = 0; dt < 3; ++dt) {
        #pragma unroll
        for (int kc = 0; kc < 4; ++kc) {
            short8v bfr[2], afr[3];
            #pragma unroll
            for (int ni = 0; ni < 2; ++ni) {
                const int n = n0w + ni*16 + lr;
                bfr[ni] = *(const short8v*)(wt1b + (size_t)n*384 + dt*128 + kc*32 + lk*8);
            }
            #pragma unroll
            for (int mi = 0; mi < 3; ++mi) {
                const int row = m0w + dt*24 + mi*16 + lr;
                afr[mi] = *(const short8v*)(smem + row*256 + ((kc*64 + lk*16) ^ ((row&7)<<4)));
            }
            #pragma unroll
            for (int mi = 0; mi < 3; ++mi)
                #pragma unroll
                for (int ni = 0; ni < 2; ++ni)
                    acc[mi][ni] = __builtin_amdgcn_mfma_f32_16x16x32_bf16(afr[mi], bfr[ni], acc[mi][ni], 0, 0, 0);
        }
    }
    {
        short8v bfr[2], afr[3];
        #pragma unroll
        for (int ni = 0; ni < 2; ++ni) {
            bfr[ni] = z8;
            if (lk == 0) bfr[ni] = *(const short8v*)(rw1b + (size_t)(n0w + ni*16 + lr)*8);
        }
        #pragma unroll
        for (int mi = 0; mi < 3; ++mi) {
            afr[mi] = z8;
            if (lk == 0) afr[mi] = *(const short8v*)(s_x6b + (m0w + mi*16 + lr + 24)*8);
        }
        #pragma unroll
        for (int mi = 0; mi < 3; ++mi)
            #pragma unroll
            for (int ni = 0; ni < 2; ++ni)
                acc[mi][ni] = __builtin_amdgcn_mfma_f32_16x16x32_bf16(afr[mi], bfr[ni], acc[mi][ni], 0, 0, 0);
    }
    __syncthreads();
    // phase E: epilogue -> f1 global + f1T LDS
    #pragma unroll
    for (int ni = 0; ni < 2; ++ni) {
        const int o = n0w + ni*16 + lr;
        const float s2 = bn12[o] * rsqrtf(bn12[384 + o] + 1e-5f);
        const float bias = (bn12[128 + o] - bn12[256 + o]*s2) + s2*tb1[o] + rb1[o];
        #pragma unroll
        for (int mi = 0; mi < 3; ++mi)
            #pragma unroll
            for (int rg = 0; rg < 4; ++rg) {
                const int rl = m0w + mi*16 + lk*4 + rg;
                const short hv = f2bf(fmaxf(acc[mi][ni][rg] + bias, 0.f));
                f1_out[(size_t)(r0 + rl)*128 + o] = hv;
                *(short*)(smem + o*FT_STRIDE + rl*2) = hv;
            }
    }
    __syncthreads();
    // phase F: premix via MFMA  fa = Amix @ f1
    {
        f32x4 pacc[3][2];
        #pragma unroll
        for (int mi = 0; mi < 3; ++mi)
            #pragma unroll
            for (int ni = 0; ni < 2; ++ni) pacc[mi][ni] = (f32x4){0.f,0.f,0.f,0.f};
        #pragma unroll
        for (int kc = 0; kc < 3; ++kc) {
            short8v bfr[2], afr[3];
            #pragma unroll
            for (int ni = 0; ni < 2; ++ni) {
                const int ch = n0w + ni*16 + lr;
                bfr[ni] = *(const short8v*)(smem + ch*FT_STRIDE + kc*64 + lk*16);
            }
            #pragma unroll
            for (int mi = 0; mi < 3; ++mi) {
                const int row = m0w + mi*16 + lr;
                afr[mi] = *(const short8v*)(amix + row*96 + kc*32 + lk*8);
            }
            #pragma unroll
            for (int mi = 0; mi < 3; ++mi)
                #pragma unroll
                for (int ni = 0; ni < 2; ++ni)
                    pacc[mi][ni] = __builtin_amdgcn_mfma_f32_16x16x32_bf16(afr[mi], bfr[ni], pacc[mi][ni], 0, 0, 0);
        }
        __syncthreads();
        #pragma unroll
        for (int ni = 0; ni < 2; ++ni) {
            const int ch2 = (n0w + ni*16 + lr) * 2;
            #pragma unroll
            for (int mi = 0; mi < 3; ++mi)
                #pragma unroll
                for (int rg = 0; rg < 4; ++rg) {
                    const int row = m0w + mi*16 + lk*4 + rg;
                    *(short*)(smem + FA_OFF + row*256 + ((ch2 & 0xF0) ^ ((row&7)<<4)) + (ch2 & 14)) =
                        f2bf(pacc[mi][ni][rg]);
                }
        }
    }
    __syncthreads();
    // phase G: gcn2 MFMA K=128 -> h2
    #pragma unroll
    for (int mi = 0; mi < 3; ++mi)
        #pragma unroll
        for (int ni = 0; ni < 2; ++ni) acc[mi][ni] = (f32x4){0.f,0.f,0.f,0.f};
    #pragma unroll
    for (int kc = 0; kc < 4; ++kc) {
        short8v bfr[2], afr[3];
        #pragma unroll
        for (int ni = 0; ni < 2; ++ni) {
            const int n = n0w + ni*16 + lr;
            bfr[ni] = *(const short8v*)(gw2b + (size_t)n*128 + kc*32 + lk*8);
        }
        #pragma unroll
        for (int mi = 0; mi < 3; ++mi) {
            const int row = m0w + mi*16 + lr;
            afr[mi] = *(const short8v*)(smem + FA_OFF + row*256 + ((kc*64 + lk*16) ^ ((row&7)<<4)));
        }
        #pragma unroll
        for (int mi = 0; mi < 3; ++mi)
            #pragma unroll
            for (int ni = 0; ni < 2; ++ni)
                acc[mi][ni] = __builtin_amdgcn_mfma_f32_16x16x32_bf16(afr[mi], bfr[ni], acc[mi][ni], 0, 0, 0);
    }
    #pragma unroll
    for (int ni = 0; ni < 2; ++ni) {
        const int o = n0w + ni*16 + lr;
        const float s = bn21[o] * rsqrtf(bn21[384 + o] + 1e-5f);
        const float t = bn21[128 + o] - bn21[256 + o]*s;
        const float g = s * gb2[o];
        #pragma unroll
        for (int mi = 0; mi < 3; ++mi)
            #pragma unroll
            for (int rg = 0; rg < 4; ++rg) {
                const int rl = m0w + mi*16 + lk*4 + rg;
                h2_out[(size_t)(r0 + rl)*128 + o] = f2bf(fmaxf(acc[mi][ni][rg] + t + g*s_cs[rl % 24], 0.f));
            }
    }
}

// ================================================================ KERNEL 2 (512 thr, XCD-chunked tiles)
// f1 residual prefetched to REGISTERS before conv2 MFMA (latency hidden; no LDS aliasing)
__global__ __launch_bounds__(512) void block2_kernel(
    const short* __restrict__ h2, const short* __restrict__ wt2b,
    const float* __restrict__ bn22, const float* __restrict__ tb2,
    const short* __restrict__ f1,
    const short* __restrict__ gw3b, const float* __restrict__ gb3, const float* __restrict__ bn31,
    const float* __restrict__ adjp, const short* __restrict__ amix,
    const char* __restrict__ zbuf,
    short* __restrict__ f2_out, short* __restrict__ h3_out)
{
    __shared__ char smem[LDS_SZ];
    float* s_cs  = (float*)(smem + TBL_OFF + 1536);

    const int cpx = gridDim.x >> 3;
    const int tile = (blockIdx.x % 8) * cpx + blockIdx.x / 8;
    const int r0 = tile * 96;
    const int bstart = (r0 / 6144) * 6144;
    const int bend = bstart + 6144;
    const int tid = threadIdx.x;
    const int l = tid & 63, wid = tid >> 6;
    const int m0w = (wid >> 2) * 48;
    const int lr = l & 15, lk = l >> 4;
    const int n0we = (wid & 3) * 32;

    if (tid < 24) s_cs[tid] = adjp[576 + tid];
    // stage h2 halo via DMA (linear dest, pre-swizzled source)
    for (int ck = wid; ck < 36; ck += 8) {
        const int row = ck*4 + (l >> 4);
        const int cg = (l & 15) ^ (row & 7);
        const int gr = r0 - 24 + row;
        const void* gsrc = (gr >= bstart && gr < bend)
            ? (const void*)(h2 + (size_t)gr*128 + cg*8)
            : (const void*)(zbuf + cg*16);
        gload_lds16(gsrc, smem + ck*1024);
    }
    // prefetch f1 residual to registers (independent of LDS; consumed after conv2)
    short resv[2][3][4];
    #pragma unroll
    for (int ni = 0; ni < 2; ++ni)
        #pragma unroll
        for (int mi = 0; mi < 3; ++mi)
            #pragma unroll
            for (int rg = 0; rg < 4; ++rg)
                resv[ni][mi][rg] = f1[(size_t)(r0 + m0w + mi*16 + lk*4 + rg)*128 + (n0we + ni*16 + lr)];
    __syncthreads();
    {
        const int n0w = n0we;
        f32x4 acc[3][2];
        #pragma unroll
        for (int mi = 0; mi < 3; ++mi)
            #pragma unroll
            for (int ni = 0; ni < 2; ++ni) acc[mi][ni] = (f32x4){0.f,0.f,0.f,0.f};
        #pragma unroll
        for (int dt = 0; dt < 3; ++dt) {
            #pragma unroll
            for (int kc = 0; kc < 4; ++kc) {
                short8v bfr[2], afr[3];
                #pragma unroll
                for (int ni = 0; ni < 2; ++ni) {
                    const int n = n0w + ni*16 + lr;
                    bfr[ni] = *(const short8v*)(wt2b + (size_t)n*384 + dt*128 + kc*32 + lk*8);
                }
                #pragma unroll
                for (int mi = 0; mi < 3; ++mi) {
                    const int row = m0w + dt*24 + mi*16 + lr;
                    afr[mi] = *(const short8v*)(smem + row*256 + ((kc*64 + lk*16) ^ ((row&7)<<4)));
                }
                #pragma unroll
                for (int mi = 0; mi < 3; ++mi)
                    #pragma unroll
                    for (int ni = 0; ni < 2; ++ni)
                        acc[mi][ni] = __builtin_amdgcn_mfma_f32_16x16x32_bf16(afr[mi], bfr[ni], acc[mi][ni], 0, 0, 0);
            }
        }
        __syncthreads();
        #pragma unroll
        for (int ni = 0; ni < 2; ++ni) {
            const int o = n0w + ni*16 + lr;
            const float s = bn22[o] * rsqrtf(bn22[384 + o] + 1e-5f);
            const float bias = (bn22[128 + o] - bn22[256 + o]*s) + s*tb2[o];
            #pragma unroll
            for (int mi = 0; mi < 3; ++mi)
                #pragma unroll
                for (int rg = 0; rg < 4; ++rg) {
                    const int rl = m0w + mi*16 + lk*4 + rg;
                    const float res = bf2f(resv[ni][mi][rg]);
                    const short hv = f2bf(fmaxf(acc[mi][ni][rg] + bias + res, 0.f));
                    *(short*)(smem + o*FT_STRIDE + rl*2) = hv;
                    f2_out[(size_t)(r0 + rl)*128 + o] = hv;
                }
        }
    }
    __syncthreads();
    {
        const int n0w = n0we;
        f32x4 pacc[3][2];
        #pragma unroll
        for (int mi = 0; mi < 3; ++mi)
            #pragma unroll
            for (int ni = 0; ni < 2; ++ni) pacc[mi][ni] = (f32x4){0.f,0.f,0.f,0.f};
        #pragma unroll
        for (int kc = 0; kc < 3; ++kc) {
            short8v bfr[2], afr[3];
            #pragma unroll
            for (int ni = 0; ni < 2; ++ni) {
                const int ch = n0w + ni*16 + lr;
                bfr[ni] = *(const short8v*)(smem + ch*FT_STRIDE + kc*64 + lk*16);
            }
            #pragma unroll
            for (int mi = 0; mi < 3; ++mi) {
                const int row = m0w + mi*16 + lr;
                afr[mi] = *(const short8v*)(amix + row*96 + kc*32 + lk*8);
            }
            #pragma unroll
            for (int mi = 0; mi < 3; ++mi)
                #pragma unroll
                for (int ni = 0; ni < 2; ++ni)
                    pacc[mi][ni] = __builtin_amdgcn_mfma_f32_16x16x32_bf16(afr[mi], bfr[ni], pacc[mi][ni], 0, 0, 0);
        }
        __syncthreads();
        #pragma unroll
        for (int ni = 0; ni < 2; ++ni) {
            const int ch2 = (n0w + ni*16 + lr) * 2;
            #pragma unroll
            for (int mi = 0; mi < 3; ++mi)
                #pragma unroll
                for (int rg = 0; rg < 4; ++rg) {
                    const int row = m0w + mi*16 + lk*4 + rg;
                    *(short*)(smem + FA_OFF + row*256 + ((ch2 & 0xF0) ^ ((row&7)<<4)) + (ch2 & 14)) =
                        f2bf(pacc[mi][ni][rg]);
                }
        }
    }
    __syncthreads();
    {
        const int n0w = (wid & 3) * 64;
        f32x4 acc[3][4];
        #pragma unroll
        for (int mi = 0; mi < 3; ++mi)
            #pragma unroll
            for (int ni = 0; ni < 4; ++ni) acc[mi][ni] = (f32x4){0.f,0.f,0.f,0.f};
        #pragma unroll
        for (int kc = 0; kc < 4; ++kc) {
            short8v bfr[4], afr[3];
            #pragma unroll
            for (int ni = 0; ni < 4; ++ni) {
                const int n = n0w + ni*16 + lr;
                bfr[ni] = *(const short8v*)(gw3b + (size_t)n*128 + kc*32 + lk*8);
            }
            #pragma unroll
            for (int mi = 0; mi < 3; ++mi) {
                const int row = m0w + mi*16 + lr;
                afr[mi] = *(const short8v*)(smem + FA_OFF + row*256 + ((kc*64 + lk*16) ^ ((row&7)<<4)));
            }
            #pragma unroll
            for (int mi = 0; mi < 3; ++mi)
                #pragma unroll
                for (int ni = 0; ni < 4; ++ni)
                    acc[mi][ni] = __builtin_amdgcn_mfma_f32_16x16x32_bf16(afr[mi], bfr[ni], acc[mi][ni], 0, 0, 0);
        }
        #pragma unroll
        for (int ni = 0; ni < 4; ++ni) {
            const int o = n0w + ni*16 + lr;
            const float s = bn31[o] * rsqrtf(bn31[768 + o] + 1e-5f);
            const float t = bn31[256 + o] - bn31[512 + o]*s;
            const float g = s * gb3[o];
            #pragma unroll
            for (int mi = 0; mi < 3; ++mi)
                #pragma unroll
                for (int rg = 0; rg < 4; ++rg) {
                    const int rl = m0w + mi*16 + lk*4 + rg;
                    h3_out[(size_t)(r0 + rl)*256 + o] = f2bf(fmaxf(acc[mi][ni][rg] + t + g*s_cs[rl % 24], 0.f));
                }
        }
    }
}

// ================================================================ KERNEL 3 (512 thr, 192-row tiles)  [round-15 proven]
__global__ __launch_bounds__(512) void conv3_pool_kernel(
    const short* __restrict__ A, const short* __restrict__ Bw,
    const float* __restrict__ bn, const float* __restrict__ tb,
    const short* __restrict__ f2, const short* __restrict__ rw3b, const float* __restrict__ rb3,
    const char* __restrict__ zbuf, float* __restrict__ pooled)
{
    __shared__ char lds[240 * 256];
    const int cpx = gridDim.x >> 3;
    const int bid = blockIdx.x;
    const int tile = (bid % 8) * cpx + bid / 8;
    const int r0 = tile * 192;
    const int bb = r0 / 6144;
    const int bstart = bb * 6144, bend = bstart + 6144;
    const int tid = threadIdx.x, l = tid & 63, wid = tid >> 6;
    const int m0w = (wid >> 2) * 96;
    const int n0w = (wid & 3) * 64;
    const int lr = l & 15, lk = l >> 4;

    f32x4 acc[6][4];
    #pragma unroll
    for (int mi = 0; mi < 6; ++mi)
        #pragma unroll
        for (int ni = 0; ni < 4; ++ni) acc[mi][ni] = (f32x4){0.f,0.f,0.f,0.f};

    for (int p = 0; p < 2; ++p) {
        if (p) __syncthreads();
        for (int ck = wid; ck < 60; ck += 8) {
            const int row = ck*4 + (l >> 4);
            const int cg = (l & 15) ^ (row & 7);
            const int gr = r0 - 24 + row;
            const void* gsrc = (gr >= bstart && gr < bend)
                ? (const void*)(A + (size_t)gr*256 + p*128 + cg*8)
                : (const void*)(zbuf + cg*16);
            gload_lds16(gsrc, lds + ck*1024);
        }
        __syncthreads();
        #pragma unroll
        for (int dt = 0; dt < 3; ++dt) {
            #pragma unroll
            for (int kc = 0; kc < 4; ++kc) {
                short8v bfr[4], afr[6];
                #pragma unroll
                for (int ni = 0; ni < 4; ++ni) {
                    const int n = n0w + ni * 16 + lr;
                    bfr[ni] = *(const short8v*)(Bw + (size_t)n * 768 + dt * 256 + p * 128 + kc * 32 + lk * 8);
                }
                #pragma unroll
                for (int mi = 0; mi < 6; ++mi) {
                    const int row = m0w + dt * 24 + mi * 16 + lr;
                    afr[mi] = *(const short8v*)(lds + row * 256 + ((kc * 64 + lk * 16) ^ ((row & 7) << 4)));
                }
                #pragma unroll
                for (int mi = 0; mi < 6; ++mi)
                    #pragma unroll
                    for (int ni = 0; ni < 4; ++ni)
                        acc[mi][ni] = __builtin_amdgcn_mfma_f32_16x16x32_bf16(afr[mi], bfr[ni], acc[mi][ni], 0, 0, 0);
            }
        }
    }
    __syncthreads();
    for (int ck = wid; ck < 48; ck += 8) {
        const int row = ck*4 + (l >> 4);
        const int cg = (l & 15) ^ (row & 7);
        gload_lds16((const void*)(f2 + (size_t)(r0 + row)*128 + cg*8), lds + ck*1024);
    }
    __syncthreads();
    #pragma unroll
    for (int kc = 0; kc < 4; ++kc) {
        short8v bfr[4], afr[6];
        #pragma unroll
        for (int ni = 0; ni < 4; ++ni) {
            const int n = n0w + ni * 16 + lr;
            bfr[ni] = *(const short8v*)(rw3b + (size_t)n * 128 + kc * 32 + lk * 8);
        }
        #pragma unroll
        for (int mi = 0; mi < 6; ++mi) {
            const int row = m0w + mi * 16 + lr;
            afr[mi] = *(const short8v*)(lds + row * 256 + ((kc * 64 + lk * 16) ^ ((row & 7) << 4)));
        }
        #pragma unroll
        for (int mi = 0; mi < 6; ++mi)
            #pragma unroll
            for (int ni = 0; ni < 4; ++ni)
                acc[mi][ni] = __builtin_amdgcn_mfma_f32_16x16x32_bf16(afr[mi], bfr[ni], acc[mi][ni], 0, 0, 0);
    }

    float psum[4] = {0.f, 0.f, 0.f, 0.f};
    #pragma unroll
    for (int ni = 0; ni < 4; ++ni) {
        const int o = n0w + ni * 16 + lr;
        const float s = bn[o] * rsqrtf(bn[768 + o] + 1e-5f);
        const float t = bn[256 + o] - bn[512 + o] * s;
        const float bias = s * tb[o] + t + rb3[o];
        #pragma unroll
        for (int mi = 0; mi < 6; ++mi)
            #pragma unroll
            for (int rg = 0; rg < 4; ++rg)
                psum[ni] += fmaxf(acc[mi][ni][rg] + bias, 0.f);
    }
    #pragma unroll
    for (int ni = 0; ni < 4; ++ni) {
        float v = psum[ni];
        v += __shfl_xor(v, 16);
        v += __shfl_xor(v, 32);
        if (l < 16) atomicAdd(pooled + (size_t)bb * 256 + (n0w + ni * 16 + l), v);
    }
}

// ---------------------------------------------------------------- head
__global__ __launch_bounds__(256) void head_kernel(const float* __restrict__ pooled_sums,
    const float* __restrict__ ow, const float* __restrict__ ob, float* __restrict__ outp) {
    __shared__ float pooled[256];
    const int b = blockIdx.x, tid = threadIdx.x;
    pooled[tid] = pooled_sums[(size_t)b*256 + tid] * (1.f/6144.f);
    __syncthreads();
    for (int rep = 0; rep < 2; ++rep) {
        const int oo = rep*256 + tid;
        float a = ob[oo];
        const float4* wr = (const float4*)(ow + (size_t)oo*256);
        for (int c4 = 0; c4 < 64; ++c4) {
            const float4 w = wr[c4];
            const float4 p = *(const float4*)&pooled[c4*4];
            a += w.x*p.x + w.y*p.y + w.z*p.z + w.w*p.w;
        }
        outp[(size_t)b*512 + oo] = a;
    }
}

// ---------------------------------------------------------------- launch
extern "C" void kernel_launch(void* const* d_in, const int* in_sizes, int n_in,
                              void* d_out, int out_size, void* d_ws, size_t ws_size,
                              hipStream_t stream)
{
    const float* x        = (const float*)d_in[0];
    const float* b1_gcn_w = (const float*)d_in[1];
    const float* b1_gcn_b = (const float*)d_in[2];
    const float* b1_bn1   = (const float*)d_in[3];
    const float* b1_tcn_w = (const float*)d_in[4];
    const float* b1_tcn_b = (const float*)d_in[5];
    const float* b1_bn2   = (const float*)d_in[6];
    const float* b1_res_w = (const float*)d_in[7];
    const float* b1_res_b = (const float*)d_in[8];
    const float* b2_gcn_w = (const float*)d_in[9];
    const float* b2_gcn_b = (const float*)d_in[10];
    const float* b2_bn1   = (const float*)d_in[11];
    const float* b2_tcn_w = (const float*)d_in[12];
    const float* b2_tcn_b = (const float*)d_in[13];
    const float* b2_bn2   = (const float*)d_in[14];
    const float* b3_gcn_w = (const float*)d_in[15];
    const float* b3_gcn_b = (const float*)d_in[16];
    const float* b3_bn1   = (const float*)d_in[17];
    const float* b3_tcn_w = (const float*)d_in[18];
    const float* b3_tcn_b = (const float*)d_in[19];
    const float* b3_bn2   = (const float*)d_in[20];
    const float* b3_res_w = (const float*)d_in[21];
    const float* b3_res_b = (const float*)d_in[22];
    const float* out_w    = (const float*)d_in[23];
    const float* out_b    = (const float*)d_in[24];

    // ---- fixed workspace carve
    char* w = (char*)d_ws;
    float* adjp = (float*)w;   w += 4096;
    short* wt1b = (short*)w;   w += 98304;
    short* wt2b = (short*)w;   w += 98304;
    short* wt3b = (short*)w;   w += 393216;
    short* gw2b = (short*)w;   w += 32768;
    short* gw3b = (short*)w;   w += 65536;
    short* rw3b = (short*)w;   w += 65536;
    short* amixb = (short*)w;  w += 18432;
    short* gw1b = (short*)w;   w += 4096;
    short* rw1b = (short*)w;   w += 4096;
    float* pooled = (float*)w; w += 32768;
    char* zbuf = w;            w += 1024;           // zero page for OOB halo DMA
    const size_t fixed = (size_t)(w - (char*)d_ws);

    // ---- adaptive batch-group: per-G bytes = 6144 * (256+256+512) = 6,291,456
    int G = 1;
    {
        const int tiers[6] = {32, 16, 8, 4, 2, 1};
        for (int ti = 0; ti < 6; ++ti) {
            const size_t need = fixed + (size_t)tiers[ti] * 6291456ull;
            if (need <= ws_size) { G = tiers[ti]; break; }
        }
    }
    const size_t MG = (size_t)G * 6144;

    short* f1 = (short*)w;           // MG*128  (also serves as f2 after block2)
    short* h2 = f1 + MG*128;         // MG*128
    short* h3 = h2 + MG*128;         // MG*256
    short* f2 = f1;                  // alias

    hipMemsetAsync(pooled, 0, 32768 + 1024, stream);  // pooled + zbuf (adjacent)
    adj_init_kernel<<<1, 256, 0, stream>>>(adjp, amixb);
    prep_kernel<<<1488, 256, 0, stream>>>(b1_tcn_w, b1_bn2, b2_tcn_w, b2_bn2, b3_tcn_w, b3_bn2,
                                          b2_gcn_w, b2_bn1, b3_gcn_w, b3_bn1, b3_res_w,
                                          b1_gcn_w, b1_bn1, b1_res_w,
                                          wt1b, wt2b, wt3b, gw2b, gw3b, rw3b, gw1b, rw1b);

    for (int b0 = 0; b0 < B_; b0 += G) {
        block1_kernel<<<64*G, 512, 0, stream>>>(
            x + (size_t)b0*6144*3,
            gw1b, b1_gcn_b, b1_bn1, rw1b, b1_res_b,
            b1_bn2, b1_tcn_b, wt1b,
            gw2b, b2_gcn_b, b2_bn1, adjp, amixb, f1, h2);
        block2_kernel<<<64*G, 512, 0, stream>>>(
            h2, wt2b, b2_bn2, b2_tcn_b, f1,
            gw3b, b3_gcn_b, b3_bn1, adjp, amixb, zbuf, f2, h3);
        conv3_pool_kernel<<<32*G, 512, 0, stream>>>(
            h3, wt3b, b3_bn2, b3_tcn_b, f2, rw3b, b3_res_b, zbuf, pooled + (size_t)b0*256);
    }

    head_kernel<<<B_, 256, 0, stream>>>(pooled, out_w, out_b, (float*)d_out);
}